// Round 1
// baseline (1258.631 us; speedup 1.0000x reference)
//
#include <hip/hip_runtime.h>
#include <cmath>

// Problem constants
// x: (B=128, S=64, N=32, C=128) fp32; qkv_w: (384,128); qkv_b: (384,)
// proj_w: (128,128); proj_b: (128,); bias_table: (225,4)
// Effective: H=4 heads, D=1024 (merged N*C/H), scale = (C/H)^-0.5 = 32^-0.5
//
// qkv element for (b,s,t,h,d): rem = t*4096 + h*1024 + d; n = rem/384; j = rem%384
//   q/k/v[b,h,s,d] = dot(x[b,s,n,:], qkv_w[j,:]) + qkv_b[j]
// attn out (b,s,h,d) -> proj-input row = s*32 + h*8 + (d>>7), col = d&127 (contiguous in d)

// ---------------- Kernel A: fused qkv + attention ----------------
// LDS layout (floats)
constexpr int XS_OFF    = 0;                 // [2][64][132] x rows (one n per slot)
constexpr int XS_SZ     = 2 * 64 * 132;      // 16896
constexpr int WB_OFF    = XS_OFF + XS_SZ;    // [32][132] W band
constexpr int WBIAS_OFF = WB_OFF + 32 * 132; // [32]
constexpr int QC_OFF    = WBIAS_OFF + 32;    // [64][36]
constexpr int KC_OFF    = QC_OFF + 64 * 36;  // [64][36]
constexpr int VC_OFF    = KC_OFF + 64 * 36;  // [64][36]
constexpr int PT_OFF    = QC_OFF;            // overlay [64][68] over qc+kc (4352 <= 4608)
constexpr int LDS_A     = VC_OFF + 64 * 36;  // 28064 floats = 112256 B

__global__ __launch_bounds__(256, 1)
void fused_qkv_attn(const float* __restrict__ x,
                    const float* __restrict__ qkv_w,
                    const float* __restrict__ qkv_b,
                    const float* __restrict__ bias_table,
                    float* __restrict__ out)
{
    __shared__ float lds[LDS_A];
    const int tid = threadIdx.x;
    const int b = blockIdx.x >> 2;
    const int h = blockIdx.x & 3;
    const int tr = tid >> 4;   // 0..15 : row group (s or t rows, strided s = tr + 16a)
    const int tc = tid & 15;   // 0..15 : col group (strided i = tc + 16g / t = tc + 16bb)

    const float* __restrict__ xb = x + (size_t)b * (64 * 32 * 128);

    int cached_n0 = -1, cached_n1 = -1;

    // Load W band (always) + x rows for this chunk's n (if changed).
    auto load_inputs = [&](int rem0, int slot) {
        const int n0 = rem0 / 384;
        const int j0 = rem0 - n0 * 384;          // multiple of 32, <= 352 (never straddles)
        int& cn = slot ? cached_n1 : cached_n0;
        if (cn != n0) {                          // block-uniform branch
            cn = n0;
            float* xsS = lds + XS_OFF + slot * (64 * 132);
            for (int f = tid; f < 64 * 32; f += 256) {
                const int r = f >> 5, c4 = f & 31;
                const float4 v = *(const float4*)(xb + ((size_t)r * 32 + n0) * 128 + c4 * 4);
                *(float4*)(xsS + r * 132 + c4 * 4) = v;
            }
        }
        for (int f = tid; f < 32 * 32; f += 256) {
            const int r = f >> 5, c4 = f & 31;
            const float4 v = *(const float4*)(qkv_w + (size_t)(j0 + r) * 128 + c4 * 4);
            *(float4*)(lds + WB_OFF + r * 132 + c4 * 4) = v;
        }
        if (tid < 32) lds[WBIAS_OFF + tid] = qkv_b[j0 + tid];
    };

    // One 64x32 (rows x chunk-cols) GEMM over K=128: dst[r][i] = dot + bias
    auto gemm_chunk = [&](int slot, int dst_off) {
        float acc[4][2] = {};
        const float* xsS = lds + XS_OFF + slot * (64 * 132);
        const float* wb  = lds + WB_OFF;
        #pragma unroll 4
        for (int c4 = 0; c4 < 32; ++c4) {
            float4 xa[4], wv[2];
            #pragma unroll
            for (int a = 0; a < 4; ++a)
                xa[a] = *(const float4*)(xsS + (tr + 16 * a) * 132 + c4 * 4);
            #pragma unroll
            for (int g = 0; g < 2; ++g)
                wv[g] = *(const float4*)(wb + (tc + 16 * g) * 132 + c4 * 4);
            #pragma unroll
            for (int a = 0; a < 4; ++a)
                #pragma unroll
                for (int g = 0; g < 2; ++g)
                    acc[a][g] += xa[a].x * wv[g].x + xa[a].y * wv[g].y
                               + xa[a].z * wv[g].z + xa[a].w * wv[g].w;
        }
        #pragma unroll
        for (int a = 0; a < 4; ++a)
            #pragma unroll
            for (int g = 0; g < 2; ++g)
                lds[dst_off + (tr + 16 * a) * 36 + tc + 16 * g] =
                    acc[a][g] + lds[WBIAS_OFF + tc + 16 * g];
    };

    // ---------------- QK^T phase ----------------
    float accL[4][4] = {};
    const int Rq = h * 1024, Rk = 4096 + h * 1024, Rv = 8192 + h * 1024;

    for (int ccc = 0; ccc < 32; ++ccc) {
        __syncthreads();                       // prev QK reads of qc/kc + Wb users done
        load_inputs(Rq + 32 * ccc, 0);
        __syncthreads();
        gemm_chunk(0, QC_OFF);
        __syncthreads();                       // q-GEMM done with Wb
        load_inputs(Rk + 32 * ccc, 1);
        __syncthreads();
        gemm_chunk(1, KC_OFF);
        __syncthreads();                       // qc,kc ready
        #pragma unroll 4
        for (int kk = 0; kk < 32; ++kk) {
            float qv[4], kv[4];
            #pragma unroll
            for (int a = 0; a < 4; ++a)  qv[a] = lds[QC_OFF + (tr + 16 * a) * 36 + kk];
            #pragma unroll
            for (int bb = 0; bb < 4; ++bb) kv[bb] = lds[KC_OFF + (tc + 16 * bb) * 36 + kk];
            #pragma unroll
            for (int a = 0; a < 4; ++a)
                #pragma unroll
                for (int bb = 0; bb < 4; ++bb)
                    accL[a][bb] += qv[a] * kv[bb];
        }
    }
    __syncthreads();   // ALL QK reads done before PT overlays qc/kc

    // ---------------- softmax (rows held by 16-lane groups sharing tr) ----------------
    const float scale = 0.17677669529663687f;  // 32^-0.5
    #pragma unroll
    for (int a = 0; a < 4; ++a) {
        const int s = tr + 16 * a;
        const int i1 = s >> 3, j1 = s & 7;
        float Lv[4];
        float m = -1e30f;
        #pragma unroll
        for (int bb = 0; bb < 4; ++bb) {
            const int t = tc + 16 * bb;
            const int i2 = t >> 3, j2 = t & 7;
            const int rel = (i1 - i2 + 7) * 15 + (j1 - j2 + 7);
            Lv[bb] = accL[a][bb] * scale + bias_table[rel * 4 + h];
            m = fmaxf(m, Lv[bb]);
        }
        m = fmaxf(m, __shfl_xor(m, 1));
        m = fmaxf(m, __shfl_xor(m, 2));
        m = fmaxf(m, __shfl_xor(m, 4));
        m = fmaxf(m, __shfl_xor(m, 8));
        float ssum = 0.f;
        #pragma unroll
        for (int bb = 0; bb < 4; ++bb) { Lv[bb] = __expf(Lv[bb] - m); ssum += Lv[bb]; }
        ssum += __shfl_xor(ssum, 1);
        ssum += __shfl_xor(ssum, 2);
        ssum += __shfl_xor(ssum, 4);
        ssum += __shfl_xor(ssum, 8);
        const float inv = 1.f / ssum;
        #pragma unroll
        for (int bb = 0; bb < 4; ++bb)
            lds[PT_OFF + (tc + 16 * bb) * 68 + s] = Lv[bb] * inv;   // PT[t][s]
    }

    // ---------------- PV phase ----------------
    for (int ccc = 0; ccc < 32; ++ccc) {
        __syncthreads();                       // PT visible / prev PV reads of vc done
        load_inputs(Rv + 32 * ccc, 0);
        __syncthreads();
        gemm_chunk(0, VC_OFF);
        __syncthreads();
        float accO[4][2] = {};
        #pragma unroll 4
        for (int kt = 0; kt < 64; ++kt) {
            float pa[4], vg[2];
            #pragma unroll
            for (int a = 0; a < 4; ++a)  pa[a] = lds[PT_OFF + kt * 68 + tr + 16 * a];
            #pragma unroll
            for (int g = 0; g < 2; ++g)  vg[g] = lds[VC_OFF + kt * 36 + tc + 16 * g];
            #pragma unroll
            for (int a = 0; a < 4; ++a)
                #pragma unroll
                for (int g = 0; g < 2; ++g)
                    accO[a][g] += pa[a] * vg[g];
        }
        #pragma unroll
        for (int a = 0; a < 4; ++a)
            #pragma unroll
            for (int g = 0; g < 2; ++g) {
                const int s = tr + 16 * a;
                const int d = 32 * ccc + tc + 16 * g;
                const int row = s * 32 + h * 8 + (d >> 7);
                out[(size_t)b * (2048 * 128) + (size_t)row * 128 + (d & 127)] = accO[a][g];
            }
    }
}

// ---------------- Kernel B: in-place proj (row-local 128->128 linear) ----------------
constexpr int LDS_B = 128 * 132 + 64 * 132;   // pwt + rows = 101376 B

__global__ __launch_bounds__(256, 1)
void proj_inplace(const float* __restrict__ pw,
                  const float* __restrict__ pb,
                  float* __restrict__ io)
{
    __shared__ float lds[LDS_B];
    float* pwt  = lds;               // [128][132], pwt[cp][c] = pw[c][cp]
    float* rows = lds + 128 * 132;   // [64][132]
    const int tid = threadIdx.x;

    for (int idx = tid; idx < 128 * 128; idx += 256) {
        const int c = idx >> 7, cp = idx & 127;
        pwt[cp * 132 + c] = pw[idx];
    }
    const int rb = tid >> 5;   // 0..7 : block of 8 rows
    const int cg = tid & 31;   // 0..31: 4 output cols
    const float4 pbv = *(const float4*)(pb + cg * 4);

    for (int it = 0; it < 8; ++it) {
        const size_t base = ((size_t)blockIdx.x * 8 + it) * 64;
        __syncthreads();                       // pwt ready / prev compute done with rows
        for (int f = tid; f < 64 * 32; f += 256) {
            const int r = f >> 5, c4 = f & 31;
            *(float4*)(rows + r * 132 + c4 * 4) =
                *(const float4*)(io + (base + r) * 128 + c4 * 4);
        }
        __syncthreads();
        float acc[8][4] = {};
        #pragma unroll 2
        for (int cp = 0; cp < 128; ++cp) {
            const float4 wv = *(const float4*)(pwt + cp * 132 + cg * 4);
            #pragma unroll
            for (int rr = 0; rr < 8; ++rr) {
                const float xv = rows[(rb * 8 + rr) * 132 + cp];
                acc[rr][0] += xv * wv.x;
                acc[rr][1] += xv * wv.y;
                acc[rr][2] += xv * wv.z;
                acc[rr][3] += xv * wv.w;
            }
        }
        #pragma unroll
        for (int rr = 0; rr < 8; ++rr) {
            float4 o;
            o.x = acc[rr][0] + pbv.x;
            o.y = acc[rr][1] + pbv.y;
            o.z = acc[rr][2] + pbv.z;
            o.w = acc[rr][3] + pbv.w;
            *(float4*)(io + (base + rb * 8 + rr) * 128 + cg * 4) = o;
        }
    }
}

extern "C" void kernel_launch(void* const* d_in, const int* in_sizes, int n_in,
                              void* d_out, int out_size, void* d_ws, size_t ws_size,
                              hipStream_t stream)
{
    const float* x          = (const float*)d_in[0];
    const float* qkv_w      = (const float*)d_in[1];
    const float* qkv_b      = (const float*)d_in[2];
    const float* proj_w     = (const float*)d_in[3];
    const float* proj_b     = (const float*)d_in[4];
    const float* bias_table = (const float*)d_in[5];
    float* out = (float*)d_out;

    // Kernel A: one block per (b, h); writes attention output into d_out
    // already laid out as proj input rows.
    fused_qkv_attn<<<dim3(128 * 4), dim3(256), 0, stream>>>(x, qkv_w, qkv_b, bias_table, out);
    // Kernel B: in-place per-row 128x128 linear (512 blocks * 8 iters * 64 rows = 262144 rows).
    proj_inplace<<<dim3(512), dim3(256), 0, stream>>>(proj_w, proj_b, out);
}

// Round 4
// 387.045 us; speedup vs baseline: 3.2519x; 3.2519x over previous
//
#include <hip/hip_runtime.h>
#include <cmath>

// Problem: x(128,64,32,128) f32; qkv_w(384,128); qkv_b(384); proj_w(128,128);
// proj_b(128); bias_table(225,4). H=4, D=1024 (merged N*C/H), scale=32^-0.5.
// qkv elem (b,s,t,h,d): rem=t*4096+h*1024+d; n=rem/384; j=rem%384 (32-chunks never straddle n).
// attn out (b,s,h,d) -> proj row = s*32+h*8+(d>>7), col = d&127.
// Per-batch strides: x = 64*32*128 = 262144 floats; out = 2048*128 = 262144 floats.

typedef short bf16x8 __attribute__((ext_vector_type(8)));
typedef float f32x4  __attribute__((ext_vector_type(4)));
#define MFMA16 __builtin_amdgcn_mfma_f32_16x16x32_bf16

__device__ __forceinline__ unsigned rne16(float f) {
    unsigned u = __float_as_uint(f);
    return (u + 0x7fffu + ((u >> 16) & 1u)) & 0xffff0000u;   // bf16 RNE, kept in high bits
}
__device__ __forceinline__ void cvt8(float4 a, float4 b, bf16x8& H, bf16x8& L) {
    float f[8] = {a.x, a.y, a.z, a.w, b.x, b.y, b.z, b.w};
    #pragma unroll
    for (int i = 0; i < 8; ++i) {
        unsigned r = rne16(f[i]);
        H[i] = (short)(r >> 16);
        float fh = __uint_as_float(r);
        L[i] = (short)(rne16(f[i] - fh) >> 16);
    }
}

// ---------------- pre-kernel: split qkv_w into hi/lo bf16, B-frag layout ----------------
// layout per 32-row band (band=j>>5): [k16 0..15][j&31 0..31][c&7 0..7]; hi at 0, lo at +49152 elems
__global__ void split_w(const float* __restrict__ qw, unsigned short* __restrict__ wsp) {
    int idx = blockIdx.x * 256 + threadIdx.x;          // 0..49151
    if (idx >= 49152) return;
    int j = idx >> 7, c = idx & 127;
    float v = qw[idx];
    unsigned r = rne16(v);
    float fh = __uint_as_float(r);
    unsigned rl = rne16(v - fh);
    int dest = (((j >> 5) * 16 + (c >> 3)) * 32 + (j & 31)) * 8 + (c & 7);
    wsp[dest] = (unsigned short)(r >> 16);
    wsp[49152 + dest] = (unsigned short)(rl >> 16);
}

// ---------------- Kernel A: fused qkv + attention (split-bf16 MFMA) ----------------
// LDS (bytes): QC 0..8320 (hi 4x1040, lo +4160)  [wave-private]
//              KC 8320..24960 (2 bufs x 8320)    [cross-wave, dbuf]
//              VC 24960..41856 (2 bufs x 8448: hi 8x528, lo +4224)
//              P  41856..50176 (8x1040, single bf16) [wave-private]
constexpr int QC_OFF = 0;
constexpr int KC_OFF = 8320;
constexpr int VC_OFF = 24960;
constexpr int P_OFF  = 41856;
constexpr int LDS_TOT = 50176;

__global__ __launch_bounds__(256, 2)
void attn_mfma(const float* __restrict__ x,
               const float* __restrict__ qkv_b,
               const float* __restrict__ bias_table,
               const unsigned short* __restrict__ wsp,
               float* __restrict__ out)
{
    __shared__ __attribute__((aligned(128))) char lds[LDS_TOT];
    const int tid = threadIdx.x;
    const int lane = tid & 63;
    const int w = tid >> 6;            // wave 0..3 -> owns rows 16w..16w+15
    const int l15 = lane & 15, lg = lane >> 4;
    const int rowbase = 16 * w;
    const int b = blockIdx.x >> 2, h = blockIdx.x & 3;
    const float* __restrict__ xb = x + (size_t)b * 262144;   // FIXED: was 524288 (2x OOB, GPU fault for b>=64)

    // per-lane x A-fragment base: row = rowbase + l15, col octet lg
    const float* xrow0 = xb + ((size_t)(rowbase + l15) * 32) * 128 + lg * 8;

    bf16x8 aH[4], aL[4];    // q-side / v-side frag cache (per ks)
    bf16x8 kH[4], kL[4];    // k-side frag cache
    int cur_na = -1, cur_nk = -1;

    auto loadfrags = [&](int n0, bf16x8 (&H)[4], bf16x8 (&L)[4]) {
        const float* p = xrow0 + (size_t)n0 * 128;
        #pragma unroll
        for (int ks = 0; ks < 4; ++ks) {
            float4 a = *(const float4*)(p + ks * 32);
            float4 c = *(const float4*)(p + ks * 32 + 4);
            cvt8(a, c, H[ks], L[ks]);
        }
    };

    // production GEMM vs W band: a0 = cols 0..15, a1 = cols 16..31 (3-pass split)
    auto mm_band = [&](const bf16x8 (&H)[4], const bf16x8 (&L)[4], int band,
                       f32x4& a0, f32x4& a1) {
        const unsigned short* wb = wsp + (size_t)band * 4096;
        #pragma unroll
        for (int ks = 0; ks < 4; ++ks) {
            int ro = ((ks * 4 + lg) * 32 + l15) * 8;
            bf16x8 b0h = *(const bf16x8*)(wb + ro);
            bf16x8 b0l = *(const bf16x8*)(wb + 49152 + ro);
            bf16x8 b1h = *(const bf16x8*)(wb + ro + 128);
            bf16x8 b1l = *(const bf16x8*)(wb + 49152 + ro + 128);
            a0 = MFMA16(H[ks], b0h, a0, 0, 0, 0);
            a0 = MFMA16(H[ks], b0l, a0, 0, 0, 0);
            a0 = MFMA16(L[ks], b0h, a0, 0, 0, 0);
            a1 = MFMA16(H[ks], b1h, a1, 0, 0, 0);
            a1 = MFMA16(H[ks], b1l, a1, 0, 0, 0);
            a1 = MFMA16(L[ks], b1h, a1, 0, 0, 0);
        }
    };

    // store production tile (rows=own 16, cols=32) as hi/lo bf16, layout [i>>3][row][i&7]
    auto store_rc = [&](char* base, f32x4 a0, f32x4 a1, float b0, float b1) {
        #pragma unroll
        for (int reg = 0; reg < 4; ++reg) {
            int s = rowbase + lg * 4 + reg;
            {
                float v = a0[reg] + b0;
                int i = l15;
                int off = (i >> 3) * 1040 + s * 16 + (i & 7) * 2;
                unsigned r = rne16(v);
                *(unsigned short*)(base + off) = (unsigned short)(r >> 16);
                *(unsigned short*)(base + 4160 + off) =
                    (unsigned short)(rne16(v - __uint_as_float(r)) >> 16);
            }
            {
                float v = a1[reg] + b1;
                int i = 16 + l15;
                int off = (i >> 3) * 1040 + s * 16 + (i & 7) * 2;
                unsigned r = rne16(v);
                *(unsigned short*)(base + off) = (unsigned short)(r >> 16);
                *(unsigned short*)(base + 4160 + off) =
                    (unsigned short)(rne16(v - __uint_as_float(r)) >> 16);
            }
        }
    };

    // ---------------- QK^T phase ----------------
    f32x4 accQK[4];
    #pragma unroll
    for (int tt = 0; tt < 4; ++tt) accQK[tt] = (f32x4){0.f, 0.f, 0.f, 0.f};

    int buf = 0;
    for (int ccc = 0; ccc < 32; ++ccc) {
        int remq = h * 1024 + 32 * ccc;
        int nq = remq / 384, j0q = remq - nq * 384, bandq = j0q >> 5;
        int remk = 4096 + h * 1024 + 32 * ccc;
        int nk = remk / 384, j0k = remk - nk * 384, bandk = j0k >> 5;
        if (nq != cur_na) { loadfrags(nq, aH, aL); cur_na = nq; }
        if (nk != cur_nk) { loadfrags(nk, kH, kL); cur_nk = nk; }

        // q-gemm -> Qc (wave-private rows)
        f32x4 q0 = (f32x4){0.f,0.f,0.f,0.f}, q1 = (f32x4){0.f,0.f,0.f,0.f};
        mm_band(aH, aL, bandq, q0, q1);
        store_rc(lds + QC_OFF, q0, q1, qkv_b[j0q + l15], qkv_b[j0q + 16 + l15]);

        // k-gemm -> Kc[buf]
        f32x4 k0 = (f32x4){0.f,0.f,0.f,0.f}, k1 = (f32x4){0.f,0.f,0.f,0.f};
        mm_band(kH, kL, bandk, k0, k1);
        store_rc(lds + KC_OFF + buf * 8320, k0, k1, qkv_b[j0k + l15], qkv_b[j0k + 16 + l15]);

        __syncthreads();

        // QK accumulate over this 32-wide d slice
        const char* qc = lds + QC_OFF + lg * 1040 + (rowbase + l15) * 16;
        bf16x8 qah = *(const bf16x8*)qc;
        bf16x8 qal = *(const bf16x8*)(qc + 4160);
        #pragma unroll
        for (int tt = 0; tt < 4; ++tt) {
            const char* kc = lds + KC_OFF + buf * 8320 + lg * 1040 + (tt * 16 + l15) * 16;
            bf16x8 kbh = *(const bf16x8*)kc;
            bf16x8 kbl = *(const bf16x8*)(kc + 4160);
            accQK[tt] = MFMA16(qah, kbh, accQK[tt], 0, 0, 0);
            accQK[tt] = MFMA16(qah, kbl, accQK[tt], 0, 0, 0);
            accQK[tt] = MFMA16(qal, kbh, accQK[tt], 0, 0, 0);
        }
        buf ^= 1;
    }

    // ---------------- softmax (rows = rowbase + lg*4 + reg) ----------------
    {
        const float scale = 0.17677669529663687f;
        #pragma unroll
        for (int reg = 0; reg < 4; ++reg) {
            int s = rowbase + lg * 4 + reg;
            int i1 = s >> 3, j1 = s & 7;
            float Lv[4];
            float m = -1e30f;
            #pragma unroll
            for (int tt = 0; tt < 4; ++tt) {
                int t = tt * 16 + l15;
                int i2 = t >> 3, j2 = t & 7;
                float L = accQK[tt][reg] * scale
                        + bias_table[((i1 - i2 + 7) * 15 + (j1 - j2 + 7)) * 4 + h];
                Lv[tt] = L;
                m = fmaxf(m, L);
            }
            m = fmaxf(m, __shfl_xor(m, 1));
            m = fmaxf(m, __shfl_xor(m, 2));
            m = fmaxf(m, __shfl_xor(m, 4));
            m = fmaxf(m, __shfl_xor(m, 8));
            float sum = 0.f;
            #pragma unroll
            for (int tt = 0; tt < 4; ++tt) { Lv[tt] = __expf(Lv[tt] - m); sum += Lv[tt]; }
            sum += __shfl_xor(sum, 1);
            sum += __shfl_xor(sum, 2);
            sum += __shfl_xor(sum, 4);
            sum += __shfl_xor(sum, 8);
            float inv = 1.f / sum;
            #pragma unroll
            for (int tt = 0; tt < 4; ++tt) {
                int t = tt * 16 + l15;
                int off = (t >> 3) * 1040 + s * 16 + (t & 7) * 2;
                *(unsigned short*)(lds + P_OFF + off) = (unsigned short)(rne16(Lv[tt] * inv) >> 16);
            }
        }
    }

    // ---------------- PV phase ----------------
    cur_na = -1;
    int bufv = 0;
    float* ob = out + (size_t)b * 262144;
    for (int ccc = 0; ccc < 32; ++ccc) {
        int remv = 8192 + h * 1024 + 32 * ccc;
        int nv = remv / 384, j0v = remv - nv * 384, bandv = j0v >> 5;
        if (nv != cur_na) { loadfrags(nv, aH, aL); cur_na = nv; }

        // v-gemm (rows = t) -> Vc[bufv], transposed store [t>>3][i][t&7]
        f32x4 v0 = (f32x4){0.f,0.f,0.f,0.f}, v1 = (f32x4){0.f,0.f,0.f,0.f};
        mm_band(aH, aL, bandv, v0, v1);
        {
            char* base = lds + VC_OFF + bufv * 8448;
            float b0 = qkv_b[j0v + l15], b1 = qkv_b[j0v + 16 + l15];
            #pragma unroll
            for (int reg = 0; reg < 4; ++reg) {
                int t = rowbase + lg * 4 + reg;
                {
                    float v = v0[reg] + b0;
                    int i = l15;
                    int off = (t >> 3) * 528 + i * 16 + (t & 7) * 2;
                    unsigned r = rne16(v);
                    *(unsigned short*)(base + off) = (unsigned short)(r >> 16);
                    *(unsigned short*)(base + 4224 + off) =
                        (unsigned short)(rne16(v - __uint_as_float(r)) >> 16);
                }
                {
                    float v = v1[reg] + b1;
                    int i = 16 + l15;
                    int off = (t >> 3) * 528 + i * 16 + (t & 7) * 2;
                    unsigned r = rne16(v);
                    *(unsigned short*)(base + off) = (unsigned short)(r >> 16);
                    *(unsigned short*)(base + 4224 + off) =
                        (unsigned short)(rne16(v - __uint_as_float(r)) >> 16);
                }
            }
        }
        __syncthreads();

        // PV: out(s, 32 cols) = P(s,64) @ V(64, 32)   (P single bf16, V hi+lo)
        f32x4 o0 = (f32x4){0.f,0.f,0.f,0.f}, o1 = (f32x4){0.f,0.f,0.f,0.f};
        #pragma unroll
        for (int ks = 0; ks < 2; ++ks) {
            bf16x8 pf = *(const bf16x8*)(lds + P_OFF + (ks * 4 + lg) * 1040 + (rowbase + l15) * 16);
            const char* vb = lds + VC_OFF + bufv * 8448 + (ks * 4 + lg) * 528;
            bf16x8 v0h = *(const bf16x8*)(vb + l15 * 16);
            bf16x8 v0l = *(const bf16x8*)(vb + 4224 + l15 * 16);
            bf16x8 v1h = *(const bf16x8*)(vb + (16 + l15) * 16);
            bf16x8 v1l = *(const bf16x8*)(vb + 4224 + (16 + l15) * 16);
            o0 = MFMA16(pf, v0h, o0, 0, 0, 0);
            o0 = MFMA16(pf, v0l, o0, 0, 0, 0);
            o1 = MFMA16(pf, v1h, o1, 0, 0, 0);
            o1 = MFMA16(pf, v1l, o1, 0, 0, 0);
        }
        bufv ^= 1;

        #pragma unroll
        for (int reg = 0; reg < 4; ++reg) {
            int s = rowbase + lg * 4 + reg;
            {
                int d = 32 * ccc + l15;
                ob[(s * 32 + h * 8 + (d >> 7)) * 128 + (d & 127)] = o0[reg];
            }
            {
                int d = 32 * ccc + 16 + l15;
                ob[(s * 32 + h * 8 + (d >> 7)) * 128 + (d & 127)] = o1[reg];
            }
        }
    }
}

// ---------------- Kernel B: in-place proj (unchanged, known-correct) ----------------
constexpr int LDS_B = 128 * 132 + 64 * 132;

__global__ __launch_bounds__(256, 1)
void proj_inplace(const float* __restrict__ pw,
                  const float* __restrict__ pb,
                  float* __restrict__ io)
{
    __shared__ float lds[LDS_B];
    float* pwt  = lds;
    float* rows = lds + 128 * 132;
    const int tid = threadIdx.x;

    for (int idx = tid; idx < 128 * 128; idx += 256) {
        const int c = idx >> 7, cp = idx & 127;
        pwt[cp * 132 + c] = pw[idx];
    }
    const int rb = tid >> 5;
    const int cg = tid & 31;
    const float4 pbv = *(const float4*)(pb + cg * 4);

    for (int it = 0; it < 8; ++it) {
        const size_t base = ((size_t)blockIdx.x * 8 + it) * 64;
        __syncthreads();
        for (int f = tid; f < 64 * 32; f += 256) {
            const int r = f >> 5, c4 = f & 31;
            *(float4*)(rows + r * 132 + c4 * 4) =
                *(const float4*)(io + (base + r) * 128 + c4 * 4);
        }
        __syncthreads();
        float acc[8][4] = {};
        #pragma unroll 2
        for (int cp = 0; cp < 128; ++cp) {
            const float4 wv = *(const float4*)(pwt + cp * 132 + cg * 4);
            #pragma unroll
            for (int rr = 0; rr < 8; ++rr) {
                const float xv = rows[(rb * 8 + rr) * 132 + cp];
                acc[rr][0] += xv * wv.x;
                acc[rr][1] += xv * wv.y;
                acc[rr][2] += xv * wv.z;
                acc[rr][3] += xv * wv.w;
            }
        }
        #pragma unroll
        for (int rr = 0; rr < 8; ++rr) {
            float4 o;
            o.x = acc[rr][0] + pbv.x;
            o.y = acc[rr][1] + pbv.y;
            o.z = acc[rr][2] + pbv.z;
            o.w = acc[rr][3] + pbv.w;
            *(float4*)(io + (base + rb * 8 + rr) * 128 + cg * 4) = o;
        }
    }
}

// ---------------- fallback fp32 kernel (round-1, known-correct) ----------------
constexpr int XS_OFF    = 0;
constexpr int XS_SZ     = 2 * 64 * 132;
constexpr int WB_OFF    = XS_OFF + XS_SZ;
constexpr int WBIAS_OFF = WB_OFF + 32 * 132;
constexpr int QCF_OFF   = WBIAS_OFF + 32;
constexpr int KCF_OFF   = QCF_OFF + 64 * 36;
constexpr int VCF_OFF   = KCF_OFF + 64 * 36;
constexpr int PT_OFF    = QCF_OFF;
constexpr int LDS_A     = VCF_OFF + 64 * 36;

__global__ __launch_bounds__(256, 1)
void fused_qkv_attn(const float* __restrict__ x,
                    const float* __restrict__ qkv_w,
                    const float* __restrict__ qkv_b,
                    const float* __restrict__ bias_table,
                    float* __restrict__ out)
{
    __shared__ float lds[LDS_A];
    const int tid = threadIdx.x;
    const int b = blockIdx.x >> 2;
    const int h = blockIdx.x & 3;
    const int tr = tid >> 4;
    const int tc = tid & 15;
    const float* __restrict__ xb = x + (size_t)b * (64 * 32 * 128);
    int cached_n0 = -1, cached_n1 = -1;

    auto load_inputs = [&](int rem0, int slot) {
        const int n0 = rem0 / 384;
        const int j0 = rem0 - n0 * 384;
        int& cn = slot ? cached_n1 : cached_n0;
        if (cn != n0) {
            cn = n0;
            float* xsS = lds + XS_OFF + slot * (64 * 132);
            for (int f = tid; f < 64 * 32; f += 256) {
                const int r = f >> 5, c4 = f & 31;
                const float4 v = *(const float4*)(xb + ((size_t)r * 32 + n0) * 128 + c4 * 4);
                *(float4*)(xsS + r * 132 + c4 * 4) = v;
            }
        }
        for (int f = tid; f < 32 * 32; f += 256) {
            const int r = f >> 5, c4 = f & 31;
            const float4 v = *(const float4*)(qkv_w + (size_t)(j0 + r) * 128 + c4 * 4);
            *(float4*)(lds + WB_OFF + r * 132 + c4 * 4) = v;
        }
        if (tid < 32) lds[WBIAS_OFF + tid] = qkv_b[j0 + tid];
    };

    auto gemm_chunk = [&](int slot, int dst_off) {
        float acc[4][2] = {};
        const float* xsS = lds + XS_OFF + slot * (64 * 132);
        const float* wb  = lds + WB_OFF;
        #pragma unroll 4
        for (int c4 = 0; c4 < 32; ++c4) {
            float4 xa[4], wv[2];
            #pragma unroll
            for (int a = 0; a < 4; ++a)
                xa[a] = *(const float4*)(xsS + (tr + 16 * a) * 132 + c4 * 4);
            #pragma unroll
            for (int g = 0; g < 2; ++g)
                wv[g] = *(const float4*)(wb + (tc + 16 * g) * 132 + c4 * 4);
            #pragma unroll
            for (int a = 0; a < 4; ++a)
                #pragma unroll
                for (int g = 0; g < 2; ++g)
                    acc[a][g] += xa[a].x * wv[g].x + xa[a].y * wv[g].y
                               + xa[a].z * wv[g].z + xa[a].w * wv[g].w;
        }
        #pragma unroll
        for (int a = 0; a < 4; ++a)
            #pragma unroll
            for (int g = 0; g < 2; ++g)
                lds[dst_off + (tr + 16 * a) * 36 + tc + 16 * g] =
                    acc[a][g] + lds[WBIAS_OFF + tc + 16 * g];
    };

    float accL[4][4] = {};
    const int Rq = h * 1024, Rk = 4096 + h * 1024, Rv = 8192 + h * 1024;

    for (int ccc = 0; ccc < 32; ++ccc) {
        __syncthreads();
        load_inputs(Rq + 32 * ccc, 0);
        __syncthreads();
        gemm_chunk(0, QCF_OFF);
        __syncthreads();
        load_inputs(Rk + 32 * ccc, 1);
        __syncthreads();
        gemm_chunk(1, KCF_OFF);
        __syncthreads();
        #pragma unroll 4
        for (int kk = 0; kk < 32; ++kk) {
            float qv[4], kv[4];
            #pragma unroll
            for (int a = 0; a < 4; ++a)  qv[a] = lds[QCF_OFF + (tr + 16 * a) * 36 + kk];
            #pragma unroll
            for (int bb = 0; bb < 4; ++bb) kv[bb] = lds[KCF_OFF + (tc + 16 * bb) * 36 + kk];
            #pragma unroll
            for (int a = 0; a < 4; ++a)
                #pragma unroll
                for (int bb = 0; bb < 4; ++bb)
                    accL[a][bb] += qv[a] * kv[bb];
        }
    }
    __syncthreads();

    const float scale = 0.17677669529663687f;
    #pragma unroll
    for (int a = 0; a < 4; ++a) {
        const int s = tr + 16 * a;
        const int i1 = s >> 3, j1 = s & 7;
        float Lv[4];
        float m = -1e30f;
        #pragma unroll
        for (int bb = 0; bb < 4; ++bb) {
            const int t = tc + 16 * bb;
            const int i2 = t >> 3, j2 = t & 7;
            const int rel = (i1 - i2 + 7) * 15 + (j1 - j2 + 7);
            Lv[bb] = accL[a][bb] * scale + bias_table[rel * 4 + h];
            m = fmaxf(m, Lv[bb]);
        }
        m = fmaxf(m, __shfl_xor(m, 1));
        m = fmaxf(m, __shfl_xor(m, 2));
        m = fmaxf(m, __shfl_xor(m, 4));
        m = fmaxf(m, __shfl_xor(m, 8));
        float ssum = 0.f;
        #pragma unroll
        for (int bb = 0; bb < 4; ++bb) { Lv[bb] = __expf(Lv[bb] - m); ssum += Lv[bb]; }
        ssum += __shfl_xor(ssum, 1);
        ssum += __shfl_xor(ssum, 2);
        ssum += __shfl_xor(ssum, 4);
        ssum += __shfl_xor(ssum, 8);
        const float inv = 1.f / ssum;
        #pragma unroll
        for (int bb = 0; bb < 4; ++bb)
            lds[PT_OFF + (tc + 16 * bb) * 68 + s] = Lv[bb] * inv;
    }

    for (int ccc = 0; ccc < 32; ++ccc) {
        __syncthreads();
        load_inputs(Rv + 32 * ccc, 0);
        __syncthreads();
        gemm_chunk(0, VCF_OFF);
        __syncthreads();
        float accO[4][2] = {};
        #pragma unroll 4
        for (int kt = 0; kt < 64; ++kt) {
            float pa[4], vg[2];
            #pragma unroll
            for (int a = 0; a < 4; ++a)  pa[a] = lds[PT_OFF + kt * 68 + tr + 16 * a];
            #pragma unroll
            for (int g = 0; g < 2; ++g)  vg[g] = lds[VCF_OFF + kt * 36 + tc + 16 * g];
            #pragma unroll
            for (int a = 0; a < 4; ++a)
                #pragma unroll
                for (int g = 0; g < 2; ++g)
                    accO[a][g] += pa[a] * vg[g];
        }
        #pragma unroll
        for (int a = 0; a < 4; ++a)
            #pragma unroll
            for (int g = 0; g < 2; ++g) {
                const int s = tr + 16 * a;
                const int d = 32 * ccc + tc + 16 * g;
                const int row = s * 32 + h * 8 + (d >> 7);
                out[(size_t)b * (2048 * 128) + (size_t)row * 128 + (d & 127)] = accO[a][g];
            }
    }
}

extern "C" void kernel_launch(void* const* d_in, const int* in_sizes, int n_in,
                              void* d_out, int out_size, void* d_ws, size_t ws_size,
                              hipStream_t stream)
{
    const float* x          = (const float*)d_in[0];
    const float* qkv_w      = (const float*)d_in[1];
    const float* qkv_b      = (const float*)d_in[2];
    const float* proj_w     = (const float*)d_in[3];
    const float* proj_b     = (const float*)d_in[4];
    const float* bias_table = (const float*)d_in[5];
    float* out = (float*)d_out;

    if (ws_size >= 196608 && d_ws != nullptr) {
        unsigned short* wsp = (unsigned short*)d_ws;
        split_w<<<dim3(192), dim3(256), 0, stream>>>(qkv_w, wsp);
        attn_mfma<<<dim3(512), dim3(256), 0, stream>>>(x, qkv_b, bias_table, wsp, out);
    } else {
        fused_qkv_attn<<<dim3(512), dim3(256), 0, stream>>>(x, qkv_w, qkv_b, bias_table, out);
    }
    proj_inplace<<<dim3(512), dim3(256), 0, stream>>>(proj_w, proj_b, out);
}

// Round 5
// 320.078 us; speedup vs baseline: 3.9323x; 1.2092x over previous
//
#include <hip/hip_runtime.h>
#include <cmath>

// Problem: x(128,64,32,128) f32; qkv_w(384,128); qkv_b(384); proj_w(128,128);
// proj_b(128); bias_table(225,4). H=4, D=1024 (merged N*C/H), scale=32^-0.5.
// qkv elem (b,s,t,h,d): rem=t*4096+h*1024+d; n=rem/384; j=rem%384 (128-chunks never straddle n or band-quad).
// attn out (b,s,h,d) -> proj row = s*32+h*8+(d>>7), col = d&127.
// Per-batch strides: x = 262144 floats; out = 262144 floats.

typedef short bf16x8 __attribute__((ext_vector_type(8)));
typedef float f32x4  __attribute__((ext_vector_type(4)));
#define MFMA16 __builtin_amdgcn_mfma_f32_16x16x32_bf16

__device__ __forceinline__ unsigned rne16(float f) {
    unsigned u = __float_as_uint(f);
    return (u + 0x7fffu + ((u >> 16) & 1u)) & 0xffff0000u;   // bf16 RNE, kept in high bits
}
__device__ __forceinline__ void cvt8(float4 a, float4 b, bf16x8& H, bf16x8& L) {
    float f[8] = {a.x, a.y, a.z, a.w, b.x, b.y, b.z, b.w};
    #pragma unroll
    for (int i = 0; i < 8; ++i) {
        unsigned r = rne16(f[i]);
        H[i] = (short)(r >> 16);
        float fh = __uint_as_float(r);
        L[i] = (short)(rne16(f[i] - fh) >> 16);
    }
}

// ---------------- pre-kernels: split weights into hi/lo bf16, B-frag layouts ----------------
// qkv_w per 32-row band (band=j>>5): [c>>3 (16)][j&31][c&7]; hi at 0, lo at +49152 shorts
__global__ void split_w(const float* __restrict__ qw, unsigned short* __restrict__ wsp) {
    int idx = blockIdx.x * 256 + threadIdx.x;          // 0..49151
    if (idx >= 49152) return;
    int j = idx >> 7, c = idx & 127;
    float v = qw[idx];
    unsigned r = rne16(v);
    unsigned rl = rne16(v - __uint_as_float(r));
    int dest = (((j >> 5) * 16 + (c >> 3)) * 32 + (j & 31)) * 8 + (c & 7);
    wsp[dest] = (unsigned short)(r >> 16);
    wsp[49152 + dest] = (unsigned short)(rl >> 16);
}
// proj_w: out[r][cp] = sum_c in[r][c]*pw[cp][c]; B[k=c][col=cp]: [(c>>3) (16)][cp (128)][c&7]
__global__ void split_pw(const float* __restrict__ pw, unsigned short* __restrict__ pwsp) {
    int idx = blockIdx.x * 256 + threadIdx.x;          // 0..16383
    if (idx >= 16384) return;
    int cp = idx >> 7, c = idx & 127;
    float v = pw[idx];
    unsigned r = rne16(v);
    unsigned rl = rne16(v - __uint_as_float(r));
    int dest = ((c >> 3) * 128 + cp) * 8 + (c & 7);
    pwsp[dest] = (unsigned short)(r >> 16);
    pwsp[16384 + dest] = (unsigned short)(rl >> 16);
}

// ---------------- Kernel A2: fused qkv + attention, 128-d chunks ----------------
// LDS: QC hi 0..16640, lo 16640..33280   ([d>>3 (16 grp x1040)][s][d&7], wave-private rows)
//      KC hi 33280, lo 49920..66560      (same layout, cross-wave, single-buffered)
//      P  66560..74880                   ([t>>3 (8 grp x1040)][s][t&7], bf16, wave-private rows)
//      VC overlays QC in PV: hi 0, lo 16640  ([t>>3 (8 grp x2080)][d (128)][t&7])
constexpr int A2_QCH = 0,     A2_QCL = 16640;
constexpr int A2_KCH = 33280, A2_KCL = 49920;
constexpr int A2_P   = 66560;
constexpr int A2_VCH = 0,     A2_VCL = 16640;
constexpr int A2_LDS = 74880;

__global__ __launch_bounds__(256, 2)
void attn_mfma2(const float* __restrict__ x,
                const float* __restrict__ qkv_b,
                const float* __restrict__ bias_table,
                const unsigned short* __restrict__ wsp,
                float* __restrict__ out)
{
    __shared__ __attribute__((aligned(128))) char lds[A2_LDS];
    const int tid = threadIdx.x;
    const int lane = tid & 63;
    const int w = tid >> 6;            // wave 0..3 -> owns rows 16w..16w+15
    const int l15 = lane & 15, lg = lane >> 4;
    const int rowbase = 16 * w;
    const int b = blockIdx.x >> 2, h = blockIdx.x & 3;
    const float* __restrict__ xb = x + (size_t)b * 262144;
    const float* xrow0 = xb + (size_t)(rowbase + l15) * 4096 + lg * 8;

    bf16x8 aH[4], aL[4];    // q-side / v-side x-frag cache
    bf16x8 kH[4], kL[4];    // k-side x-frag cache
    int cur_na = -1, cur_nk = -1;

    auto loadfrags = [&](int n0, bf16x8 (&H)[4], bf16x8 (&L)[4]) {
        const float* p = xrow0 + (size_t)n0 * 128;
        #pragma unroll
        for (int ks = 0; ks < 4; ++ks) {
            float4 a = *(const float4*)(p + ks * 32);
            float4 c = *(const float4*)(p + ks * 32 + 4);
            cvt8(a, c, H[ks], L[ks]);
        }
    };

    // production: rows = own 16, cols = 128 (j0..j0+127, 4 bands), K=128, 3-pass split
    auto prod128 = [&](const bf16x8 (&H)[4], const bf16x8 (&L)[4], int j0, f32x4 (&acc)[8]) {
        const unsigned short* wb = wsp + (size_t)(j0 >> 5) * 4096;
        #pragma unroll
        for (int ks = 0; ks < 4; ++ks) {
            #pragma unroll
            for (int ct = 0; ct < 8; ++ct) {
                int ro = (ct >> 1) * 4096 + ((ks * 4 + lg) * 32 + (ct & 1) * 16 + l15) * 8;
                bf16x8 bh = *(const bf16x8*)(wb + ro);
                bf16x8 bl = *(const bf16x8*)(wb + 49152 + ro);
                acc[ct] = MFMA16(H[ks], bh, acc[ct], 0, 0, 0);
                acc[ct] = MFMA16(H[ks], bl, acc[ct], 0, 0, 0);
                acc[ct] = MFMA16(L[ks], bh, acc[ct], 0, 0, 0);
            }
        }
    };

    // store production tile (+bias) as hi/lo bf16 into [d>>3][s][d&7] layout
    auto storeQK = [&](int hbase, int lbase, f32x4 (&acc)[8], int j0) {
        #pragma unroll
        for (int ct = 0; ct < 8; ++ct) {
            float bias = qkv_b[j0 + ct * 16 + l15];
            int d = ct * 16 + l15;
            int dofs = (d >> 3) * 1040 + (d & 7) * 2;
            #pragma unroll
            for (int reg = 0; reg < 4; ++reg) {
                int s = rowbase + lg * 4 + reg;
                float v = acc[ct][reg] + bias;
                unsigned r = rne16(v);
                *(unsigned short*)(lds + hbase + dofs + s * 16) = (unsigned short)(r >> 16);
                *(unsigned short*)(lds + lbase + dofs + s * 16) =
                    (unsigned short)(rne16(v - __uint_as_float(r)) >> 16);
            }
        }
    };

    // ---------------- QK^T phase (8 iters of 128 d) ----------------
    f32x4 accQK[4];
    #pragma unroll
    for (int tt = 0; tt < 4; ++tt) accQK[tt] = (f32x4){0.f, 0.f, 0.f, 0.f};

    for (int cc = 0; cc < 8; ++cc) {
        int remq = h * 1024 + 128 * cc;
        int nq = remq / 384, j0q = remq - nq * 384;
        int remk = 4096 + h * 1024 + 128 * cc;
        int nk = remk / 384, j0k = remk - nk * 384;
        if (nq != cur_na) { loadfrags(nq, aH, aL); cur_na = nq; }
        if (nk != cur_nk) { loadfrags(nk, kH, kL); cur_nk = nk; }

        f32x4 qa[8];
        #pragma unroll
        for (int i = 0; i < 8; ++i) qa[i] = (f32x4){0.f, 0.f, 0.f, 0.f};
        prod128(aH, aL, j0q, qa);
        storeQK(A2_QCH, A2_QCL, qa, j0q);

        f32x4 ka[8];
        #pragma unroll
        for (int i = 0; i < 8; ++i) ka[i] = (f32x4){0.f, 0.f, 0.f, 0.f};
        prod128(kH, kL, j0k, ka);
        storeQK(A2_KCH, A2_KCL, ka, j0k);

        __syncthreads();   // KC ready (QC wave-private)

        #pragma unroll
        for (int kst = 0; kst < 4; ++kst) {
            int grp = (kst * 4 + lg) * 1040;
            bf16x8 qh = *(const bf16x8*)(lds + A2_QCH + grp + (rowbase + l15) * 16);
            bf16x8 ql = *(const bf16x8*)(lds + A2_QCL + grp + (rowbase + l15) * 16);
            #pragma unroll
            for (int tt = 0; tt < 4; ++tt) {
                bf16x8 kh = *(const bf16x8*)(lds + A2_KCH + grp + (tt * 16 + l15) * 16);
                bf16x8 kl = *(const bf16x8*)(lds + A2_KCL + grp + (tt * 16 + l15) * 16);
                accQK[tt] = MFMA16(qh, kh, accQK[tt], 0, 0, 0);
                accQK[tt] = MFMA16(qh, kl, accQK[tt], 0, 0, 0);
                accQK[tt] = MFMA16(ql, kh, accQK[tt], 0, 0, 0);
            }
        }
        __syncthreads();   // KC consumed, next iter may overwrite
    }

    // ---------------- softmax (rows = rowbase + lg*4 + reg) ----------------
    {
        const float scale = 0.17677669529663687f;
        #pragma unroll
        for (int reg = 0; reg < 4; ++reg) {
            int s = rowbase + lg * 4 + reg;
            int i1 = s >> 3, j1 = s & 7;
            float Lv[4];
            float m = -1e30f;
            #pragma unroll
            for (int tt = 0; tt < 4; ++tt) {
                int t = tt * 16 + l15;
                int i2 = t >> 3, j2 = t & 7;
                float L = accQK[tt][reg] * scale
                        + bias_table[((i1 - i2 + 7) * 15 + (j1 - j2 + 7)) * 4 + h];
                Lv[tt] = L;
                m = fmaxf(m, L);
            }
            m = fmaxf(m, __shfl_xor(m, 1));
            m = fmaxf(m, __shfl_xor(m, 2));
            m = fmaxf(m, __shfl_xor(m, 4));
            m = fmaxf(m, __shfl_xor(m, 8));
            float sum = 0.f;
            #pragma unroll
            for (int tt = 0; tt < 4; ++tt) { Lv[tt] = __expf(Lv[tt] - m); sum += Lv[tt]; }
            sum += __shfl_xor(sum, 1);
            sum += __shfl_xor(sum, 2);
            sum += __shfl_xor(sum, 4);
            sum += __shfl_xor(sum, 8);
            float inv = 1.f / sum;
            #pragma unroll
            for (int tt = 0; tt < 4; ++tt) {
                int t = tt * 16 + l15;
                int off = (t >> 3) * 1040 + s * 16 + (t & 7) * 2;
                *(unsigned short*)(lds + A2_P + off) = (unsigned short)(rne16(Lv[tt] * inv) >> 16);
            }
        }
    }
    __syncthreads();   // all QK reads of QC done before VC overlays it

    // ---------------- PV phase (8 iters of 128 d) ----------------
    cur_na = -1;
    float* ob = out + (size_t)b * 262144;
    for (int cc = 0; cc < 8; ++cc) {
        int remv = 8192 + h * 1024 + 128 * cc;
        int nv = remv / 384, j0v = remv - nv * 384;
        if (nv != cur_na) { loadfrags(nv, aH, aL); cur_na = nv; }

        f32x4 va[8];
        #pragma unroll
        for (int i = 0; i < 8; ++i) va[i] = (f32x4){0.f, 0.f, 0.f, 0.f};
        prod128(aH, aL, j0v, va);

        // transposed store into VC [t>>3][d][t&7]
        #pragma unroll
        for (int ct = 0; ct < 8; ++ct) {
            float bias = qkv_b[j0v + ct * 16 + l15];
            int d = ct * 16 + l15;
            #pragma unroll
            for (int reg = 0; reg < 4; ++reg) {
                int t = rowbase + lg * 4 + reg;
                float v = va[ct][reg] + bias;
                int off = (t >> 3) * 2080 + d * 16 + (t & 7) * 2;
                unsigned r = rne16(v);
                *(unsigned short*)(lds + A2_VCH + off) = (unsigned short)(r >> 16);
                *(unsigned short*)(lds + A2_VCL + off) =
                    (unsigned short)(rne16(v - __uint_as_float(r)) >> 16);
            }
        }
        __syncthreads();   // VC ready

        f32x4 o[8];
        #pragma unroll
        for (int i = 0; i < 8; ++i) o[i] = (f32x4){0.f, 0.f, 0.f, 0.f};
        #pragma unroll
        for (int kst = 0; kst < 2; ++kst) {
            bf16x8 pf = *(const bf16x8*)(lds + A2_P + (kst * 4 + lg) * 1040 + (rowbase + l15) * 16);
            int vgrp = (kst * 4 + lg) * 2080;
            #pragma unroll
            for (int dt = 0; dt < 8; ++dt) {
                bf16x8 vh = *(const bf16x8*)(lds + A2_VCH + vgrp + (dt * 16 + l15) * 16);
                bf16x8 vl = *(const bf16x8*)(lds + A2_VCL + vgrp + (dt * 16 + l15) * 16);
                o[dt] = MFMA16(pf, vh, o[dt], 0, 0, 0);
                o[dt] = MFMA16(pf, vl, o[dt], 0, 0, 0);
            }
        }
        __syncthreads();   // VC consumed

        #pragma unroll
        for (int reg = 0; reg < 4; ++reg) {
            int s = rowbase + lg * 4 + reg;
            float* orow = ob + (size_t)(s * 32 + h * 8 + cc) * 128;
            #pragma unroll
            for (int dt = 0; dt < 8; ++dt)
                orow[dt * 16 + l15] = o[dt][reg];
        }
    }
}

// ---------------- Kernel B2: proj via MFMA, register-only ----------------
__global__ __launch_bounds__(256, 4)
void proj_mfma(const unsigned short* __restrict__ pwsp,
               const float* __restrict__ pb,
               float* __restrict__ io)
{
    const int tid = threadIdx.x;
    const int lane = tid & 63;
    const int w = tid >> 6;
    const int l15 = lane & 15, lg = lane >> 4;
    const size_t rbase = (size_t)blockIdx.x * 64 + w * 16;

    // load own 16 rows (K=128) as A-frags, split hi/lo
    const float* rp = io + (rbase + l15) * 128 + lg * 8;
    bf16x8 aH[4], aL[4];
    #pragma unroll
    for (int ks = 0; ks < 4; ++ks) {
        float4 a = *(const float4*)(rp + ks * 32);
        float4 c = *(const float4*)(rp + ks * 32 + 4);
        cvt8(a, c, aH[ks], aL[ks]);
    }

    f32x4 acc[8];
    #pragma unroll
    for (int i = 0; i < 8; ++i) acc[i] = (f32x4){0.f, 0.f, 0.f, 0.f};

    #pragma unroll
    for (int ks = 0; ks < 4; ++ks) {
        #pragma unroll
        for (int ct = 0; ct < 8; ++ct) {
            int ro = ((ks * 4 + lg) * 128 + ct * 16 + l15) * 8;
            bf16x8 bh = *(const bf16x8*)(pwsp + ro);
            bf16x8 bl = *(const bf16x8*)(pwsp + 16384 + ro);
            acc[ct] = MFMA16(aH[ks], bh, acc[ct], 0, 0, 0);
            acc[ct] = MFMA16(aH[ks], bl, acc[ct], 0, 0, 0);
            acc[ct] = MFMA16(aL[ks], bh, acc[ct], 0, 0, 0);
        }
    }

    #pragma unroll
    for (int ct = 0; ct < 8; ++ct) {
        float bias = pb[ct * 16 + l15];
        #pragma unroll
        for (int reg = 0; reg < 4; ++reg)
            io[(rbase + lg * 4 + reg) * 128 + ct * 16 + l15] = acc[ct][reg] + bias;
    }
}

// ---------------- round-4 kernels (kept as mid/fallback paths, known-correct) ----------------
constexpr int QC_OFF = 0;
constexpr int KC_OFF = 8320;
constexpr int VC_OFF = 24960;
constexpr int P_OFF  = 41856;
constexpr int LDS_TOT = 50176;

__global__ __launch_bounds__(256, 2)
void attn_mfma(const float* __restrict__ x,
               const float* __restrict__ qkv_b,
               const float* __restrict__ bias_table,
               const unsigned short* __restrict__ wsp,
               float* __restrict__ out)
{
    __shared__ __attribute__((aligned(128))) char lds[LDS_TOT];
    const int tid = threadIdx.x;
    const int lane = tid & 63;
    const int w = tid >> 6;
    const int l15 = lane & 15, lg = lane >> 4;
    const int rowbase = 16 * w;
    const int b = blockIdx.x >> 2, h = blockIdx.x & 3;
    const float* __restrict__ xb = x + (size_t)b * 262144;
    const float* xrow0 = xb + ((size_t)(rowbase + l15) * 32) * 128 + lg * 8;

    bf16x8 aH[4], aL[4];
    bf16x8 kH[4], kL[4];
    int cur_na = -1, cur_nk = -1;

    auto loadfrags = [&](int n0, bf16x8 (&H)[4], bf16x8 (&L)[4]) {
        const float* p = xrow0 + (size_t)n0 * 128;
        #pragma unroll
        for (int ks = 0; ks < 4; ++ks) {
            float4 a = *(const float4*)(p + ks * 32);
            float4 c = *(const float4*)(p + ks * 32 + 4);
            cvt8(a, c, H[ks], L[ks]);
        }
    };

    auto mm_band = [&](const bf16x8 (&H)[4], const bf16x8 (&L)[4], int band,
                       f32x4& a0, f32x4& a1) {
        const unsigned short* wb = wsp + (size_t)band * 4096;
        #pragma unroll
        for (int ks = 0; ks < 4; ++ks) {
            int ro = ((ks * 4 + lg) * 32 + l15) * 8;
            bf16x8 b0h = *(const bf16x8*)(wb + ro);
            bf16x8 b0l = *(const bf16x8*)(wb + 49152 + ro);
            bf16x8 b1h = *(const bf16x8*)(wb + ro + 128);
            bf16x8 b1l = *(const bf16x8*)(wb + 49152 + ro + 128);
            a0 = MFMA16(H[ks], b0h, a0, 0, 0, 0);
            a0 = MFMA16(H[ks], b0l, a0, 0, 0, 0);
            a0 = MFMA16(L[ks], b0h, a0, 0, 0, 0);
            a1 = MFMA16(H[ks], b1h, a1, 0, 0, 0);
            a1 = MFMA16(H[ks], b1l, a1, 0, 0, 0);
            a1 = MFMA16(L[ks], b1h, a1, 0, 0, 0);
        }
    };

    auto store_rc = [&](char* base, f32x4 a0, f32x4 a1, float b0, float b1) {
        #pragma unroll
        for (int reg = 0; reg < 4; ++reg) {
            int s = rowbase + lg * 4 + reg;
            {
                float v = a0[reg] + b0;
                int i = l15;
                int off = (i >> 3) * 1040 + s * 16 + (i & 7) * 2;
                unsigned r = rne16(v);
                *(unsigned short*)(base + off) = (unsigned short)(r >> 16);
                *(unsigned short*)(base + 4160 + off) =
                    (unsigned short)(rne16(v - __uint_as_float(r)) >> 16);
            }
            {
                float v = a1[reg] + b1;
                int i = 16 + l15;
                int off = (i >> 3) * 1040 + s * 16 + (i & 7) * 2;
                unsigned r = rne16(v);
                *(unsigned short*)(base + off) = (unsigned short)(r >> 16);
                *(unsigned short*)(base + 4160 + off) =
                    (unsigned short)(rne16(v - __uint_as_float(r)) >> 16);
            }
        }
    };

    f32x4 accQK[4];
    #pragma unroll
    for (int tt = 0; tt < 4; ++tt) accQK[tt] = (f32x4){0.f, 0.f, 0.f, 0.f};

    int buf = 0;
    for (int ccc = 0; ccc < 32; ++ccc) {
        int remq = h * 1024 + 32 * ccc;
        int nq = remq / 384, j0q = remq - nq * 384, bandq = j0q >> 5;
        int remk = 4096 + h * 1024 + 32 * ccc;
        int nk = remk / 384, j0k = remk - nk * 384, bandk = j0k >> 5;
        if (nq != cur_na) { loadfrags(nq, aH, aL); cur_na = nq; }
        if (nk != cur_nk) { loadfrags(nk, kH, kL); cur_nk = nk; }

        f32x4 q0 = (f32x4){0.f,0.f,0.f,0.f}, q1 = (f32x4){0.f,0.f,0.f,0.f};
        mm_band(aH, aL, bandq, q0, q1);
        store_rc(lds + QC_OFF, q0, q1, qkv_b[j0q + l15], qkv_b[j0q + 16 + l15]);

        f32x4 k0 = (f32x4){0.f,0.f,0.f,0.f}, k1 = (f32x4){0.f,0.f,0.f,0.f};
        mm_band(kH, kL, bandk, k0, k1);
        store_rc(lds + KC_OFF + buf * 8320, k0, k1, qkv_b[j0k + l15], qkv_b[j0k + 16 + l15]);

        __syncthreads();

        const char* qc = lds + QC_OFF + lg * 1040 + (rowbase + l15) * 16;
        bf16x8 qah = *(const bf16x8*)qc;
        bf16x8 qal = *(const bf16x8*)(qc + 4160);
        #pragma unroll
        for (int tt = 0; tt < 4; ++tt) {
            const char* kc = lds + KC_OFF + buf * 8320 + lg * 1040 + (tt * 16 + l15) * 16;
            bf16x8 kbh = *(const bf16x8*)kc;
            bf16x8 kbl = *(const bf16x8*)(kc + 4160);
            accQK[tt] = MFMA16(qah, kbh, accQK[tt], 0, 0, 0);
            accQK[tt] = MFMA16(qah, kbl, accQK[tt], 0, 0, 0);
            accQK[tt] = MFMA16(qal, kbh, accQK[tt], 0, 0, 0);
        }
        buf ^= 1;
    }

    {
        const float scale = 0.17677669529663687f;
        #pragma unroll
        for (int reg = 0; reg < 4; ++reg) {
            int s = rowbase + lg * 4 + reg;
            int i1 = s >> 3, j1 = s & 7;
            float Lv[4];
            float m = -1e30f;
            #pragma unroll
            for (int tt = 0; tt < 4; ++tt) {
                int t = tt * 16 + l15;
                int i2 = t >> 3, j2 = t & 7;
                float L = accQK[tt][reg] * scale
                        + bias_table[((i1 - i2 + 7) * 15 + (j1 - j2 + 7)) * 4 + h];
                Lv[tt] = L;
                m = fmaxf(m, L);
            }
            m = fmaxf(m, __shfl_xor(m, 1));
            m = fmaxf(m, __shfl_xor(m, 2));
            m = fmaxf(m, __shfl_xor(m, 4));
            m = fmaxf(m, __shfl_xor(m, 8));
            float sum = 0.f;
            #pragma unroll
            for (int tt = 0; tt < 4; ++tt) { Lv[tt] = __expf(Lv[tt] - m); sum += Lv[tt]; }
            sum += __shfl_xor(sum, 1);
            sum += __shfl_xor(sum, 2);
            sum += __shfl_xor(sum, 4);
            sum += __shfl_xor(sum, 8);
            float inv = 1.f / sum;
            #pragma unroll
            for (int tt = 0; tt < 4; ++tt) {
                int t = tt * 16 + l15;
                int off = (t >> 3) * 1040 + s * 16 + (t & 7) * 2;
                *(unsigned short*)(lds + P_OFF + off) = (unsigned short)(rne16(Lv[tt] * inv) >> 16);
            }
        }
    }

    cur_na = -1;
    int bufv = 0;
    float* ob = out + (size_t)b * 262144;
    for (int ccc = 0; ccc < 32; ++ccc) {
        int remv = 8192 + h * 1024 + 32 * ccc;
        int nv = remv / 384, j0v = remv - nv * 384, bandv = j0v >> 5;
        if (nv != cur_na) { loadfrags(nv, aH, aL); cur_na = nv; }

        f32x4 v0 = (f32x4){0.f,0.f,0.f,0.f}, v1 = (f32x4){0.f,0.f,0.f,0.f};
        mm_band(aH, aL, bandv, v0, v1);
        {
            char* base = lds + VC_OFF + bufv * 8448;
            float b0 = qkv_b[j0v + l15], b1 = qkv_b[j0v + 16 + l15];
            #pragma unroll
            for (int reg = 0; reg < 4; ++reg) {
                int t = rowbase + lg * 4 + reg;
                {
                    float v = v0[reg] + b0;
                    int i = l15;
                    int off = (t >> 3) * 528 + i * 16 + (t & 7) * 2;
                    unsigned r = rne16(v);
                    *(unsigned short*)(base + off) = (unsigned short)(r >> 16);
                    *(unsigned short*)(base + 4224 + off) =
                        (unsigned short)(rne16(v - __uint_as_float(r)) >> 16);
                }
                {
                    float v = v1[reg] + b1;
                    int i = 16 + l15;
                    int off = (t >> 3) * 528 + i * 16 + (t & 7) * 2;
                    unsigned r = rne16(v);
                    *(unsigned short*)(base + off) = (unsigned short)(r >> 16);
                    *(unsigned short*)(base + 4224 + off) =
                        (unsigned short)(rne16(v - __uint_as_float(r)) >> 16);
                }
            }
        }
        __syncthreads();

        f32x4 o0 = (f32x4){0.f,0.f,0.f,0.f}, o1 = (f32x4){0.f,0.f,0.f,0.f};
        #pragma unroll
        for (int ks = 0; ks < 2; ++ks) {
            bf16x8 pf = *(const bf16x8*)(lds + P_OFF + (ks * 4 + lg) * 1040 + (rowbase + l15) * 16);
            const char* vb = lds + VC_OFF + bufv * 8448 + (ks * 4 + lg) * 528;
            bf16x8 v0h = *(const bf16x8*)(vb + l15 * 16);
            bf16x8 v0l = *(const bf16x8*)(vb + 4224 + l15 * 16);
            bf16x8 v1h = *(const bf16x8*)(vb + (16 + l15) * 16);
            bf16x8 v1l = *(const bf16x8*)(vb + 4224 + (16 + l15) * 16);
            o0 = MFMA16(pf, v0h, o0, 0, 0, 0);
            o0 = MFMA16(pf, v0l, o0, 0, 0, 0);
            o1 = MFMA16(pf, v1h, o1, 0, 0, 0);
            o1 = MFMA16(pf, v1l, o1, 0, 0, 0);
        }
        bufv ^= 1;

        #pragma unroll
        for (int reg = 0; reg < 4; ++reg) {
            int s = rowbase + lg * 4 + reg;
            {
                int d = 32 * ccc + l15;
                ob[(s * 32 + h * 8 + (d >> 7)) * 128 + (d & 127)] = o0[reg];
            }
            {
                int d = 32 * ccc + 16 + l15;
                ob[(s * 32 + h * 8 + (d >> 7)) * 128 + (d & 127)] = o1[reg];
            }
        }
    }
}

constexpr int LDS_B = 128 * 132 + 64 * 132;

__global__ __launch_bounds__(256, 1)
void proj_inplace(const float* __restrict__ pw,
                  const float* __restrict__ pb,
                  float* __restrict__ io)
{
    __shared__ float lds[LDS_B];
    float* pwt  = lds;
    float* rows = lds + 128 * 132;
    const int tid = threadIdx.x;

    for (int idx = tid; idx < 128 * 128; idx += 256) {
        const int c = idx >> 7, cp = idx & 127;
        pwt[cp * 132 + c] = pw[idx];
    }
    const int rb = tid >> 5;
    const int cg = tid & 31;
    const float4 pbv = *(const float4*)(pb + cg * 4);

    for (int it = 0; it < 8; ++it) {
        const size_t base = ((size_t)blockIdx.x * 8 + it) * 64;
        __syncthreads();
        for (int f = tid; f < 64 * 32; f += 256) {
            const int r = f >> 5, c4 = f & 31;
            *(float4*)(rows + r * 132 + c4 * 4) =
                *(const float4*)(io + (base + r) * 128 + c4 * 4);
        }
        __syncthreads();
        float acc[8][4] = {};
        #pragma unroll 2
        for (int cp = 0; cp < 128; ++cp) {
            const float4 wv = *(const float4*)(pwt + cp * 132 + cg * 4);
            #pragma unroll
            for (int rr = 0; rr < 8; ++rr) {
                const float xv = rows[(rb * 8 + rr) * 132 + cp];
                acc[rr][0] += xv * wv.x;
                acc[rr][1] += xv * wv.y;
                acc[rr][2] += xv * wv.z;
                acc[rr][3] += xv * wv.w;
            }
        }
        #pragma unroll
        for (int rr = 0; rr < 8; ++rr) {
            float4 o;
            o.x = acc[rr][0] + pbv.x;
            o.y = acc[rr][1] + pbv.y;
            o.z = acc[rr][2] + pbv.z;
            o.w = acc[rr][3] + pbv.w;
            *(float4*)(io + (base + rb * 8 + rr) * 128 + cg * 4) = o;
        }
    }
}

constexpr int XS_OFF    = 0;
constexpr int XS_SZ     = 2 * 64 * 132;
constexpr int WB_OFF    = XS_OFF + XS_SZ;
constexpr int WBIAS_OFF = WB_OFF + 32 * 132;
constexpr int QCF_OFF   = WBIAS_OFF + 32;
constexpr int KCF_OFF   = QCF_OFF + 64 * 36;
constexpr int VCF_OFF   = KCF_OFF + 64 * 36;
constexpr int PT_OFF    = QCF_OFF;
constexpr int LDS_A     = VCF_OFF + 64 * 36;

__global__ __launch_bounds__(256, 1)
void fused_qkv_attn(const float* __restrict__ x,
                    const float* __restrict__ qkv_w,
                    const float* __restrict__ qkv_b,
                    const float* __restrict__ bias_table,
                    float* __restrict__ out)
{
    __shared__ float lds[LDS_A];
    const int tid = threadIdx.x;
    const int b = blockIdx.x >> 2;
    const int h = blockIdx.x & 3;
    const int tr = tid >> 4;
    const int tc = tid & 15;
    const float* __restrict__ xb = x + (size_t)b * (64 * 32 * 128);
    int cached_n0 = -1, cached_n1 = -1;

    auto load_inputs = [&](int rem0, int slot) {
        const int n0 = rem0 / 384;
        const int j0 = rem0 - n0 * 384;
        int& cn = slot ? cached_n1 : cached_n0;
        if (cn != n0) {
            cn = n0;
            float* xsS = lds + XS_OFF + slot * (64 * 132);
            for (int f = tid; f < 64 * 32; f += 256) {
                const int r = f >> 5, c4 = f & 31;
                const float4 v = *(const float4*)(xb + ((size_t)r * 32 + n0) * 128 + c4 * 4);
                *(float4*)(xsS + r * 132 + c4 * 4) = v;
            }
        }
        for (int f = tid; f < 32 * 32; f += 256) {
            const int r = f >> 5, c4 = f & 31;
            const float4 v = *(const float4*)(qkv_w + (size_t)(j0 + r) * 128 + c4 * 4);
            *(float4*)(lds + WB_OFF + r * 132 + c4 * 4) = v;
        }
        if (tid < 32) lds[WBIAS_OFF + tid] = qkv_b[j0 + tid];
    };

    auto gemm_chunk = [&](int slot, int dst_off) {
        float acc[4][2] = {};
        const float* xsS = lds + XS_OFF + slot * (64 * 132);
        const float* wb  = lds + WB_OFF;
        #pragma unroll 4
        for (int c4 = 0; c4 < 32; ++c4) {
            float4 xa[4], wv[2];
            #pragma unroll
            for (int a = 0; a < 4; ++a)
                xa[a] = *(const float4*)(xsS + (tr + 16 * a) * 132 + c4 * 4);
            #pragma unroll
            for (int g = 0; g < 2; ++g)
                wv[g] = *(const float4*)(wb + (tc + 16 * g) * 132 + c4 * 4);
            #pragma unroll
            for (int a = 0; a < 4; ++a)
                #pragma unroll
                for (int g = 0; g < 2; ++g)
                    acc[a][g] += xa[a].x * wv[g].x + xa[a].y * wv[g].y
                               + xa[a].z * wv[g].z + xa[a].w * wv[g].w;
        }
        #pragma unroll
        for (int a = 0; a < 4; ++a)
            #pragma unroll
            for (int g = 0; g < 2; ++g)
                lds[dst_off + (tr + 16 * a) * 36 + tc + 16 * g] =
                    acc[a][g] + lds[WBIAS_OFF + tc + 16 * g];
    };

    float accL[4][4] = {};
    const int Rq = h * 1024, Rk = 4096 + h * 1024, Rv = 8192 + h * 1024;

    for (int ccc = 0; ccc < 32; ++ccc) {
        __syncthreads();
        load_inputs(Rq + 32 * ccc, 0);
        __syncthreads();
        gemm_chunk(0, QCF_OFF);
        __syncthreads();
        load_inputs(Rk + 32 * ccc, 1);
        __syncthreads();
        gemm_chunk(1, KCF_OFF);
        __syncthreads();
        #pragma unroll 4
        for (int kk = 0; kk < 32; ++kk) {
            float qv[4], kv[4];
            #pragma unroll
            for (int a = 0; a < 4; ++a)  qv[a] = lds[QCF_OFF + (tr + 16 * a) * 36 + kk];
            #pragma unroll
            for (int bb = 0; bb < 4; ++bb) kv[bb] = lds[KCF_OFF + (tc + 16 * bb) * 36 + kk];
            #pragma unroll
            for (int a = 0; a < 4; ++a)
                #pragma unroll
                for (int bb = 0; bb < 4; ++bb)
                    accL[a][bb] += qv[a] * kv[bb];
        }
    }
    __syncthreads();

    const float scale = 0.17677669529663687f;
    #pragma unroll
    for (int a = 0; a < 4; ++a) {
        const int s = tr + 16 * a;
        const int i1 = s >> 3, j1 = s & 7;
        float Lv[4];
        float m = -1e30f;
        #pragma unroll
        for (int bb = 0; bb < 4; ++bb) {
            const int t = tc + 16 * bb;
            const int i2 = t >> 3, j2 = t & 7;
            const int rel = (i1 - i2 + 7) * 15 + (j1 - j2 + 7);
            Lv[bb] = accL[a][bb] * scale + bias_table[rel * 4 + h];
            m = fmaxf(m, Lv[bb]);
        }
        m = fmaxf(m, __shfl_xor(m, 1));
        m = fmaxf(m, __shfl_xor(m, 2));
        m = fmaxf(m, __shfl_xor(m, 4));
        m = fmaxf(m, __shfl_xor(m, 8));
        float ssum = 0.f;
        #pragma unroll
        for (int bb = 0; bb < 4; ++bb) { Lv[bb] = __expf(Lv[bb] - m); ssum += Lv[bb]; }
        ssum += __shfl_xor(ssum, 1);
        ssum += __shfl_xor(ssum, 2);
        ssum += __shfl_xor(ssum, 4);
        ssum += __shfl_xor(ssum, 8);
        const float inv = 1.f / ssum;
        #pragma unroll
        for (int bb = 0; bb < 4; ++bb)
            lds[PT_OFF + (tc + 16 * bb) * 68 + s] = Lv[bb] * inv;
    }

    for (int ccc = 0; ccc < 32; ++ccc) {
        __syncthreads();
        load_inputs(Rv + 32 * ccc, 0);
        __syncthreads();
        gemm_chunk(0, VCF_OFF);
        __syncthreads();
        float accO[4][2] = {};
        #pragma unroll 4
        for (int kt = 0; kt < 64; ++kt) {
            float pa[4], vg[2];
            #pragma unroll
            for (int a = 0; a < 4; ++a)  pa[a] = lds[PT_OFF + kt * 68 + tr + 16 * a];
            #pragma unroll
            for (int g = 0; g < 2; ++g)  vg[g] = lds[VCF_OFF + kt * 36 + tc + 16 * g];
            #pragma unroll
            for (int a = 0; a < 4; ++a)
                #pragma unroll
                for (int g = 0; g < 2; ++g)
                    accO[a][g] += pa[a] * vg[g];
        }
        #pragma unroll
        for (int a = 0; a < 4; ++a)
            #pragma unroll
            for (int g = 0; g < 2; ++g) {
                const int s = tr + 16 * a;
                const int d = 32 * ccc + tc + 16 * g;
                const int row = s * 32 + h * 8 + (d >> 7);
                out[(size_t)b * (2048 * 128) + (size_t)row * 128 + (d & 127)] = accO[a][g];
            }
    }
}

extern "C" void kernel_launch(void* const* d_in, const int* in_sizes, int n_in,
                              void* d_out, int out_size, void* d_ws, size_t ws_size,
                              hipStream_t stream)
{
    const float* x          = (const float*)d_in[0];
    const float* qkv_w      = (const float*)d_in[1];
    const float* qkv_b      = (const float*)d_in[2];
    const float* proj_w     = (const float*)d_in[3];
    const float* proj_b     = (const float*)d_in[4];
    const float* bias_table = (const float*)d_in[5];
    float* out = (float*)d_out;

    if (ws_size >= 262144 && d_ws != nullptr) {
        unsigned short* wsp = (unsigned short*)d_ws;
        split_w<<<dim3(192), dim3(256), 0, stream>>>(qkv_w, wsp);
        split_pw<<<dim3(64), dim3(256), 0, stream>>>(proj_w, wsp + 98304);
        attn_mfma2<<<dim3(512), dim3(256), 0, stream>>>(x, qkv_b, bias_table, wsp, out);
        proj_mfma<<<dim3(4096), dim3(256), 0, stream>>>(wsp + 98304, proj_b, out);
    } else if (ws_size >= 196608 && d_ws != nullptr) {
        unsigned short* wsp = (unsigned short*)d_ws;
        split_w<<<dim3(192), dim3(256), 0, stream>>>(qkv_w, wsp);
        attn_mfma<<<dim3(512), dim3(256), 0, stream>>>(x, qkv_b, bias_table, wsp, out);
        proj_inplace<<<dim3(512), dim3(256), 0, stream>>>(proj_w, proj_b, out);
    } else {
        fused_qkv_attn<<<dim3(512), dim3(256), 0, stream>>>(x, qkv_w, qkv_b, bias_table, out);
        proj_inplace<<<dim3(512), dim3(256), 0, stream>>>(proj_w, proj_b, out);
    }
}

// Round 6
// 294.074 us; speedup vs baseline: 4.2800x; 1.0884x over previous
//
#include <hip/hip_runtime.h>
#include <cmath>

// Problem: x(128,64,32,128) f32; qkv_w(384,128); qkv_b(384); proj_w(128,128);
// proj_b(128); bias_table(225,4). H=4, D=1024 (merged N*C/H), scale=32^-0.5.
// qkv elem (b,s,t,h,d): rem=t*4096+h*1024+d; n=rem/384; j=rem%384 (128-chunks never straddle n; j0 in {0,128,256}).
// attn out (b,s,h,d) -> proj row = s*32+h*8+(d>>7), col = d&127.
// Per-batch strides: x = 262144 floats; out = 262144 floats.

typedef short bf16x8 __attribute__((ext_vector_type(8)));
typedef float f32x4  __attribute__((ext_vector_type(4)));
#define MFMA16 __builtin_amdgcn_mfma_f32_16x16x32_bf16

__device__ __forceinline__ unsigned rne16(float f) {
    unsigned u = __float_as_uint(f);
    return (u + 0x7fffu + ((u >> 16) & 1u)) & 0xffff0000u;   // bf16 RNE, kept in high bits
}
__device__ __forceinline__ void cvt8(float4 a, float4 b, bf16x8& H, bf16x8& L) {
    float f[8] = {a.x, a.y, a.z, a.w, b.x, b.y, b.z, b.w};
    #pragma unroll
    for (int i = 0; i < 8; ++i) {
        unsigned r = rne16(f[i]);
        H[i] = (short)(r >> 16);
        float fh = __uint_as_float(r);
        L[i] = (short)(rne16(f[i] - fh) >> 16);
    }
}

// ---------------- pre-kernels: split weights into hi/lo bf16, B-frag layouts ----------------
__global__ void split_w(const float* __restrict__ qw, unsigned short* __restrict__ wsp) {
    int idx = blockIdx.x * 256 + threadIdx.x;          // 0..49151
    if (idx >= 49152) return;
    int j = idx >> 7, c = idx & 127;
    float v = qw[idx];
    unsigned r = rne16(v);
    unsigned rl = rne16(v - __uint_as_float(r));
    int dest = (((j >> 5) * 16 + (c >> 3)) * 32 + (j & 31)) * 8 + (c & 7);
    wsp[dest] = (unsigned short)(r >> 16);
    wsp[49152 + dest] = (unsigned short)(rl >> 16);
}
__global__ void split_pw(const float* __restrict__ pw, unsigned short* __restrict__ pwsp) {
    int idx = blockIdx.x * 256 + threadIdx.x;          // 0..16383
    if (idx >= 16384) return;
    int cp = idx >> 7, c = idx & 127;
    float v = pw[idx];
    unsigned r = rne16(v);
    unsigned rl = rne16(v - __uint_as_float(r));
    int dest = ((c >> 3) * 128 + cp) * 8 + (c & 7);
    pwsp[dest] = (unsigned short)(r >> 16);
    pwsp[16384 + dest] = (unsigned short)(rl >> 16);
}

// ---------------- Kernel A3: fused qkv + attention, 8 waves/block ----------------
// wave w: qt=w&3 (16-row tile), ch=w>>2 (64-col half of the 128-d chunk / 32-t half / 64-d out half)
// LDS: QC hi 0 lo 16640 ([d>>3 16x1040][s 64][d&7]) ; KC hi 33280 lo 49920 (same)
//      P 66560..74880 ([t>>3 8x1040][s][t&7] bf16) ; SMA 74880 [2][64] f32 ; SMB 75392 [2][64] f32
//      VC overlays QC in PV: hi 0 lo 16640 ([t>>3 8x2080][d 128][t&7])
constexpr int A3_QCH = 0,     A3_QCL = 16640;
constexpr int A3_KCH = 33280, A3_KCL = 49920;
constexpr int A3_P   = 66560;
constexpr int A3_SMA = 74880;
constexpr int A3_SMB = 75392;
constexpr int A3_VCH = 0,     A3_VCL = 16640;
constexpr int A3_LDS = 75904;

__global__ __launch_bounds__(512, 4)
void attn_mfma3(const float* __restrict__ x,
                const float* __restrict__ qkv_b,
                const float* __restrict__ bias_table,
                const unsigned short* __restrict__ wsp,
                float* __restrict__ out)
{
    __shared__ __attribute__((aligned(128))) char lds[A3_LDS];
    const int tid = threadIdx.x;
    const int lane = tid & 63;
    const int w = tid >> 6;
    const int l15 = lane & 15, lg = lane >> 4;
    const int qt = w & 3, ch = w >> 2;
    const int rowbase = qt * 16;
    const int b = blockIdx.x >> 2, h = blockIdx.x & 3;
    const float* __restrict__ xb = x + (size_t)b * 262144;
    const float* xrow0 = xb + (size_t)(rowbase + l15) * 4096 + lg * 8;

    bf16x8 aH[4], aL[4];    // q-side / v-side x-frag cache
    bf16x8 kH[4], kL[4];    // k-side x-frag cache
    int cur_na = -1, cur_nk = -1;

    auto loadfrags = [&](int n0, bf16x8 (&H)[4], bf16x8 (&L)[4]) {
        const float* p = xrow0 + (size_t)n0 * 128;
        #pragma unroll
        for (int ks = 0; ks < 4; ++ks) {
            float4 a = *(const float4*)(p + ks * 32);
            float4 c = *(const float4*)(p + ks * 32 + 4);
            cvt8(a, c, H[ks], L[ks]);
        }
    };

    // production: rows = own 16, cols = wave's 64-half of [j0..j0+127], K=128, 3-pass split
    auto prod64 = [&](const bf16x8 (&H)[4], const bf16x8 (&L)[4], int j0, f32x4 (&acc)[4]) {
        const unsigned short* wb = wsp + (size_t)(j0 >> 5) * 4096;
        #pragma unroll
        for (int ks = 0; ks < 4; ++ks) {
            #pragma unroll
            for (int ct = 0; ct < 4; ++ct) {
                int gct = ch * 4 + ct;
                int ro = (gct >> 1) * 4096 + ((ks * 4 + lg) * 32 + (gct & 1) * 16 + l15) * 8;
                bf16x8 bh = *(const bf16x8*)(wb + ro);
                bf16x8 bl = *(const bf16x8*)(wb + 49152 + ro);
                acc[ct] = MFMA16(H[ks], bh, acc[ct], 0, 0, 0);
                acc[ct] = MFMA16(H[ks], bl, acc[ct], 0, 0, 0);
                acc[ct] = MFMA16(L[ks], bh, acc[ct], 0, 0, 0);
            }
        }
    };

    // store production tile (+bias) as hi/lo bf16 into [d>>3][s][d&7]
    auto storeP64 = [&](int hbase, int lbase, f32x4 (&acc)[4], int j0) {
        #pragma unroll
        for (int ct = 0; ct < 4; ++ct) {
            int d = (ch * 4 + ct) * 16 + l15;
            float bias = qkv_b[j0 + d];
            int dofs = (d >> 3) * 1040 + (d & 7) * 2;
            #pragma unroll
            for (int reg = 0; reg < 4; ++reg) {
                int s = rowbase + lg * 4 + reg;
                float v = acc[ct][reg] + bias;
                unsigned r = rne16(v);
                *(unsigned short*)(lds + hbase + dofs + s * 16) = (unsigned short)(r >> 16);
                *(unsigned short*)(lds + lbase + dofs + s * 16) =
                    (unsigned short)(rne16(v - __uint_as_float(r)) >> 16);
            }
        }
    };

    // ---------------- QK^T phase (8 iters of 128 d) ----------------
    f32x4 accQK[2];
    #pragma unroll
    for (int tt = 0; tt < 2; ++tt) accQK[tt] = (f32x4){0.f, 0.f, 0.f, 0.f};

    for (int cc = 0; cc < 8; ++cc) {
        int remq = h * 1024 + 128 * cc;
        int nq = remq / 384, j0q = remq - nq * 384;
        int remk = 4096 + h * 1024 + 128 * cc;
        int nk = remk / 384, j0k = remk - nk * 384;
        if (nq != cur_na) { loadfrags(nq, aH, aL); cur_na = nq; }
        if (nk != cur_nk) { loadfrags(nk, kH, kL); cur_nk = nk; }

        f32x4 qa[4];
        #pragma unroll
        for (int i = 0; i < 4; ++i) qa[i] = (f32x4){0.f, 0.f, 0.f, 0.f};
        prod64(aH, aL, j0q, qa);
        storeP64(A3_QCH, A3_QCL, qa, j0q);

        f32x4 ka[4];
        #pragma unroll
        for (int i = 0; i < 4; ++i) ka[i] = (f32x4){0.f, 0.f, 0.f, 0.f};
        prod64(kH, kL, j0k, ka);
        storeP64(A3_KCH, A3_KCL, ka, j0k);

        __syncthreads();   // QC,KC ready (cross-wave)

        #pragma unroll
        for (int kst = 0; kst < 4; ++kst) {
            int grp = (kst * 4 + lg) * 1040;
            bf16x8 qh = *(const bf16x8*)(lds + A3_QCH + grp + (rowbase + l15) * 16);
            bf16x8 ql = *(const bf16x8*)(lds + A3_QCL + grp + (rowbase + l15) * 16);
            #pragma unroll
            for (int tt = 0; tt < 2; ++tt) {
                int trow = ((ch * 2 + tt) * 16 + l15) * 16;
                bf16x8 kh = *(const bf16x8*)(lds + A3_KCH + grp + trow);
                bf16x8 kl = *(const bf16x8*)(lds + A3_KCL + grp + trow);
                accQK[tt] = MFMA16(qh, kh, accQK[tt], 0, 0, 0);
                accQK[tt] = MFMA16(qh, kl, accQK[tt], 0, 0, 0);
                accQK[tt] = MFMA16(ql, kh, accQK[tt], 0, 0, 0);
            }
        }
        __syncthreads();   // consumed; next iter may overwrite
    }

    // ---------------- softmax: rows s = rowbase+lg*4+reg, wave holds t-half (32) ----------------
    {
        const float scale = 0.17677669529663687f;
        float* smA = (float*)(lds + A3_SMA);
        float* smB = (float*)(lds + A3_SMB);
        float ex[4][2];
        #pragma unroll
        for (int reg = 0; reg < 4; ++reg) {
            int s = rowbase + lg * 4 + reg;
            int i1 = s >> 3, j1 = s & 7;
            float m = -1e30f;
            #pragma unroll
            for (int tt = 0; tt < 2; ++tt) {
                int t = (ch * 2 + tt) * 16 + l15;
                int i2 = t >> 3, j2 = t & 7;
                float L = accQK[tt][reg] * scale
                        + bias_table[((i1 - i2 + 7) * 15 + (j1 - j2 + 7)) * 4 + h];
                ex[reg][tt] = L;
                m = fmaxf(m, L);
            }
            m = fmaxf(m, __shfl_xor(m, 1));
            m = fmaxf(m, __shfl_xor(m, 2));
            m = fmaxf(m, __shfl_xor(m, 4));
            m = fmaxf(m, __shfl_xor(m, 8));
            if (l15 == 0) smA[ch * 64 + s] = m;
        }
        __syncthreads();
        #pragma unroll
        for (int reg = 0; reg < 4; ++reg) {
            int s = rowbase + lg * 4 + reg;
            float mg = fmaxf(smA[s], smA[64 + s]);
            float e0 = __expf(ex[reg][0] - mg);
            float e1 = __expf(ex[reg][1] - mg);
            ex[reg][0] = e0; ex[reg][1] = e1;
            float sum = e0 + e1;
            sum += __shfl_xor(sum, 1);
            sum += __shfl_xor(sum, 2);
            sum += __shfl_xor(sum, 4);
            sum += __shfl_xor(sum, 8);
            if (l15 == 0) smB[ch * 64 + s] = sum;
        }
        __syncthreads();
        #pragma unroll
        for (int reg = 0; reg < 4; ++reg) {
            int s = rowbase + lg * 4 + reg;
            float inv = 1.f / (smB[s] + smB[64 + s]);
            #pragma unroll
            for (int tt = 0; tt < 2; ++tt) {
                int t = (ch * 2 + tt) * 16 + l15;
                int off = (t >> 3) * 1040 + s * 16 + (t & 7) * 2;
                *(unsigned short*)(lds + A3_P + off) =
                    (unsigned short)(rne16(ex[reg][tt] * inv) >> 16);
            }
        }
    }
    // NOTE: VC overlays QC; all QC reads finished before the softmax barriers.
    // P stores become visible via the first PV barrier below.

    // ---------------- PV phase (8 iters of 128 d) ----------------
    cur_na = -1;
    float* ob = out + (size_t)b * 262144;
    for (int cc = 0; cc < 8; ++cc) {
        int remv = 8192 + h * 1024 + 128 * cc;
        int nv = remv / 384, j0v = remv - nv * 384;
        if (nv != cur_na) { loadfrags(nv, aH, aL); cur_na = nv; }

        f32x4 va[4];
        #pragma unroll
        for (int i = 0; i < 4; ++i) va[i] = (f32x4){0.f, 0.f, 0.f, 0.f};
        prod64(aH, aL, j0v, va);

        // transposed store into VC [t>>3][d][t&7]
        #pragma unroll
        for (int ct = 0; ct < 4; ++ct) {
            int d = (ch * 4 + ct) * 16 + l15;
            float bias = qkv_b[j0v + d];
            #pragma unroll
            for (int reg = 0; reg < 4; ++reg) {
                int t = rowbase + lg * 4 + reg;
                float v = va[ct][reg] + bias;
                int off = (t >> 3) * 2080 + d * 16 + (t & 7) * 2;
                unsigned r = rne16(v);
                *(unsigned short*)(lds + A3_VCH + off) = (unsigned short)(r >> 16);
                *(unsigned short*)(lds + A3_VCL + off) =
                    (unsigned short)(rne16(v - __uint_as_float(r)) >> 16);
            }
        }
        __syncthreads();   // VC (and on cc=0, P) ready

        f32x4 o[4];
        #pragma unroll
        for (int i = 0; i < 4; ++i) o[i] = (f32x4){0.f, 0.f, 0.f, 0.f};
        #pragma unroll
        for (int kst = 0; kst < 2; ++kst) {
            bf16x8 pf = *(const bf16x8*)(lds + A3_P + (kst * 4 + lg) * 1040 + (rowbase + l15) * 16);
            int vgrp = (kst * 4 + lg) * 2080;
            #pragma unroll
            for (int dt = 0; dt < 4; ++dt) {
                int drow = ((ch * 4 + dt) * 16 + l15) * 16;
                bf16x8 vh = *(const bf16x8*)(lds + A3_VCH + vgrp + drow);
                bf16x8 vl = *(const bf16x8*)(lds + A3_VCL + vgrp + drow);
                o[dt] = MFMA16(pf, vh, o[dt], 0, 0, 0);
                o[dt] = MFMA16(pf, vl, o[dt], 0, 0, 0);
            }
        }
        __syncthreads();   // VC consumed

        #pragma unroll
        for (int reg = 0; reg < 4; ++reg) {
            int s = rowbase + lg * 4 + reg;
            float* orow = ob + (size_t)(s * 32 + h * 8 + cc) * 128;
            #pragma unroll
            for (int dt = 0; dt < 4; ++dt)
                orow[(ch * 4 + dt) * 16 + l15] = o[dt][reg];
        }
    }
}

// ---------------- Kernel B2: proj via MFMA, register-only (at HBM roofline) ----------------
__global__ __launch_bounds__(256, 4)
void proj_mfma(const unsigned short* __restrict__ pwsp,
               const float* __restrict__ pb,
               float* __restrict__ io)
{
    const int tid = threadIdx.x;
    const int lane = tid & 63;
    const int w = tid >> 6;
    const int l15 = lane & 15, lg = lane >> 4;
    const size_t rbase = (size_t)blockIdx.x * 64 + w * 16;

    const float* rp = io + (rbase + l15) * 128 + lg * 8;
    bf16x8 aH[4], aL[4];
    #pragma unroll
    for (int ks = 0; ks < 4; ++ks) {
        float4 a = *(const float4*)(rp + ks * 32);
        float4 c = *(const float4*)(rp + ks * 32 + 4);
        cvt8(a, c, aH[ks], aL[ks]);
    }

    f32x4 acc[8];
    #pragma unroll
    for (int i = 0; i < 8; ++i) acc[i] = (f32x4){0.f, 0.f, 0.f, 0.f};

    #pragma unroll
    for (int ks = 0; ks < 4; ++ks) {
        #pragma unroll
        for (int ct = 0; ct < 8; ++ct) {
            int ro = ((ks * 4 + lg) * 128 + ct * 16 + l15) * 8;
            bf16x8 bh = *(const bf16x8*)(pwsp + ro);
            bf16x8 bl = *(const bf16x8*)(pwsp + 16384 + ro);
            acc[ct] = MFMA16(aH[ks], bh, acc[ct], 0, 0, 0);
            acc[ct] = MFMA16(aH[ks], bl, acc[ct], 0, 0, 0);
            acc[ct] = MFMA16(aL[ks], bh, acc[ct], 0, 0, 0);
        }
    }

    #pragma unroll
    for (int ct = 0; ct < 8; ++ct) {
        float bias = pb[ct * 16 + l15];
        #pragma unroll
        for (int reg = 0; reg < 4; ++reg)
            io[(rbase + lg * 4 + reg) * 128 + ct * 16 + l15] = acc[ct][reg] + bias;
    }
}

// ---------------- round-4 kernels (fallback paths, known-correct) ----------------
constexpr int QC_OFF = 0;
constexpr int KC_OFF = 8320;
constexpr int VC_OFF = 24960;
constexpr int P_OFF  = 41856;
constexpr int LDS_TOT = 50176;

__global__ __launch_bounds__(256, 2)
void attn_mfma(const float* __restrict__ x,
               const float* __restrict__ qkv_b,
               const float* __restrict__ bias_table,
               const unsigned short* __restrict__ wsp,
               float* __restrict__ out)
{
    __shared__ __attribute__((aligned(128))) char lds[LDS_TOT];
    const int tid = threadIdx.x;
    const int lane = tid & 63;
    const int w = tid >> 6;
    const int l15 = lane & 15, lg = lane >> 4;
    const int rowbase = 16 * w;
    const int b = blockIdx.x >> 2, h = blockIdx.x & 3;
    const float* __restrict__ xb = x + (size_t)b * 262144;
    const float* xrow0 = xb + ((size_t)(rowbase + l15) * 32) * 128 + lg * 8;

    bf16x8 aH[4], aL[4];
    bf16x8 kH[4], kL[4];
    int cur_na = -1, cur_nk = -1;

    auto loadfrags = [&](int n0, bf16x8 (&H)[4], bf16x8 (&L)[4]) {
        const float* p = xrow0 + (size_t)n0 * 128;
        #pragma unroll
        for (int ks = 0; ks < 4; ++ks) {
            float4 a = *(const float4*)(p + ks * 32);
            float4 c = *(const float4*)(p + ks * 32 + 4);
            cvt8(a, c, H[ks], L[ks]);
        }
    };

    auto mm_band = [&](const bf16x8 (&H)[4], const bf16x8 (&L)[4], int band,
                       f32x4& a0, f32x4& a1) {
        const unsigned short* wb = wsp + (size_t)band * 4096;
        #pragma unroll
        for (int ks = 0; ks < 4; ++ks) {
            int ro = ((ks * 4 + lg) * 32 + l15) * 8;
            bf16x8 b0h = *(const bf16x8*)(wb + ro);
            bf16x8 b0l = *(const bf16x8*)(wb + 49152 + ro);
            bf16x8 b1h = *(const bf16x8*)(wb + ro + 128);
            bf16x8 b1l = *(const bf16x8*)(wb + 49152 + ro + 128);
            a0 = MFMA16(H[ks], b0h, a0, 0, 0, 0);
            a0 = MFMA16(H[ks], b0l, a0, 0, 0, 0);
            a0 = MFMA16(L[ks], b0h, a0, 0, 0, 0);
            a1 = MFMA16(H[ks], b1h, a1, 0, 0, 0);
            a1 = MFMA16(H[ks], b1l, a1, 0, 0, 0);
            a1 = MFMA16(L[ks], b1h, a1, 0, 0, 0);
        }
    };

    auto store_rc = [&](char* base, f32x4 a0, f32x4 a1, float b0, float b1) {
        #pragma unroll
        for (int reg = 0; reg < 4; ++reg) {
            int s = rowbase + lg * 4 + reg;
            {
                float v = a0[reg] + b0;
                int i = l15;
                int off = (i >> 3) * 1040 + s * 16 + (i & 7) * 2;
                unsigned r = rne16(v);
                *(unsigned short*)(base + off) = (unsigned short)(r >> 16);
                *(unsigned short*)(base + 4160 + off) =
                    (unsigned short)(rne16(v - __uint_as_float(r)) >> 16);
            }
            {
                float v = a1[reg] + b1;
                int i = 16 + l15;
                int off = (i >> 3) * 1040 + s * 16 + (i & 7) * 2;
                unsigned r = rne16(v);
                *(unsigned short*)(base + off) = (unsigned short)(r >> 16);
                *(unsigned short*)(base + 4160 + off) =
                    (unsigned short)(rne16(v - __uint_as_float(r)) >> 16);
            }
        }
    };

    f32x4 accQK[4];
    #pragma unroll
    for (int tt = 0; tt < 4; ++tt) accQK[tt] = (f32x4){0.f, 0.f, 0.f, 0.f};

    int buf = 0;
    for (int ccc = 0; ccc < 32; ++ccc) {
        int remq = h * 1024 + 32 * ccc;
        int nq = remq / 384, j0q = remq - nq * 384, bandq = j0q >> 5;
        int remk = 4096 + h * 1024 + 32 * ccc;
        int nk = remk / 384, j0k = remk - nk * 384, bandk = j0k >> 5;
        if (nq != cur_na) { loadfrags(nq, aH, aL); cur_na = nq; }
        if (nk != cur_nk) { loadfrags(nk, kH, kL); cur_nk = nk; }

        f32x4 q0 = (f32x4){0.f,0.f,0.f,0.f}, q1 = (f32x4){0.f,0.f,0.f,0.f};
        mm_band(aH, aL, bandq, q0, q1);
        store_rc(lds + QC_OFF, q0, q1, qkv_b[j0q + l15], qkv_b[j0q + 16 + l15]);

        f32x4 k0 = (f32x4){0.f,0.f,0.f,0.f}, k1 = (f32x4){0.f,0.f,0.f,0.f};
        mm_band(kH, kL, bandk, k0, k1);
        store_rc(lds + KC_OFF + buf * 8320, k0, k1, qkv_b[j0k + l15], qkv_b[j0k + 16 + l15]);

        __syncthreads();

        const char* qc = lds + QC_OFF + lg * 1040 + (rowbase + l15) * 16;
        bf16x8 qah = *(const bf16x8*)qc;
        bf16x8 qal = *(const bf16x8*)(qc + 4160);
        #pragma unroll
        for (int tt = 0; tt < 4; ++tt) {
            const char* kc = lds + KC_OFF + buf * 8320 + lg * 1040 + (tt * 16 + l15) * 16;
            bf16x8 kbh = *(const bf16x8*)kc;
            bf16x8 kbl = *(const bf16x8*)(kc + 4160);
            accQK[tt] = MFMA16(qah, kbh, accQK[tt], 0, 0, 0);
            accQK[tt] = MFMA16(qah, kbl, accQK[tt], 0, 0, 0);
            accQK[tt] = MFMA16(qal, kbh, accQK[tt], 0, 0, 0);
        }
        buf ^= 1;
    }

    {
        const float scale = 0.17677669529663687f;
        #pragma unroll
        for (int reg = 0; reg < 4; ++reg) {
            int s = rowbase + lg * 4 + reg;
            int i1 = s >> 3, j1 = s & 7;
            float Lv[4];
            float m = -1e30f;
            #pragma unroll
            for (int tt = 0; tt < 4; ++tt) {
                int t = tt * 16 + l15;
                int i2 = t >> 3, j2 = t & 7;
                float L = accQK[tt][reg] * scale
                        + bias_table[((i1 - i2 + 7) * 15 + (j1 - j2 + 7)) * 4 + h];
                Lv[tt] = L;
                m = fmaxf(m, L);
            }
            m = fmaxf(m, __shfl_xor(m, 1));
            m = fmaxf(m, __shfl_xor(m, 2));
            m = fmaxf(m, __shfl_xor(m, 4));
            m = fmaxf(m, __shfl_xor(m, 8));
            float sum = 0.f;
            #pragma unroll
            for (int tt = 0; tt < 4; ++tt) { Lv[tt] = __expf(Lv[tt] - m); sum += Lv[tt]; }
            sum += __shfl_xor(sum, 1);
            sum += __shfl_xor(sum, 2);
            sum += __shfl_xor(sum, 4);
            sum += __shfl_xor(sum, 8);
            float inv = 1.f / sum;
            #pragma unroll
            for (int tt = 0; tt < 4; ++tt) {
                int t = tt * 16 + l15;
                int off = (t >> 3) * 1040 + s * 16 + (t & 7) * 2;
                *(unsigned short*)(lds + P_OFF + off) = (unsigned short)(rne16(Lv[tt] * inv) >> 16);
            }
        }
    }

    cur_na = -1;
    int bufv = 0;
    float* ob = out + (size_t)b * 262144;
    for (int ccc = 0; ccc < 32; ++ccc) {
        int remv = 8192 + h * 1024 + 32 * ccc;
        int nv = remv / 384, j0v = remv - nv * 384, bandv = j0v >> 5;
        if (nv != cur_na) { loadfrags(nv, aH, aL); cur_na = nv; }

        f32x4 v0 = (f32x4){0.f,0.f,0.f,0.f}, v1 = (f32x4){0.f,0.f,0.f,0.f};
        mm_band(aH, aL, bandv, v0, v1);
        {
            char* base = lds + VC_OFF + bufv * 8448;
            float b0 = qkv_b[j0v + l15], b1 = qkv_b[j0v + 16 + l15];
            #pragma unroll
            for (int reg = 0; reg < 4; ++reg) {
                int t = rowbase + lg * 4 + reg;
                {
                    float v = v0[reg] + b0;
                    int i = l15;
                    int off = (t >> 3) * 528 + i * 16 + (t & 7) * 2;
                    unsigned r = rne16(v);
                    *(unsigned short*)(base + off) = (unsigned short)(r >> 16);
                    *(unsigned short*)(base + 4224 + off) =
                        (unsigned short)(rne16(v - __uint_as_float(r)) >> 16);
                }
                {
                    float v = v1[reg] + b1;
                    int i = 16 + l15;
                    int off = (t >> 3) * 528 + i * 16 + (t & 7) * 2;
                    unsigned r = rne16(v);
                    *(unsigned short*)(base + off) = (unsigned short)(r >> 16);
                    *(unsigned short*)(base + 4224 + off) =
                        (unsigned short)(rne16(v - __uint_as_float(r)) >> 16);
                }
            }
        }
        __syncthreads();

        f32x4 o0 = (f32x4){0.f,0.f,0.f,0.f}, o1 = (f32x4){0.f,0.f,0.f,0.f};
        #pragma unroll
        for (int ks = 0; ks < 2; ++ks) {
            bf16x8 pf = *(const bf16x8*)(lds + P_OFF + (ks * 4 + lg) * 1040 + (rowbase + l15) * 16);
            const char* vb = lds + VC_OFF + bufv * 8448 + (ks * 4 + lg) * 528;
            bf16x8 v0h = *(const bf16x8*)(vb + l15 * 16);
            bf16x8 v0l = *(const bf16x8*)(vb + 4224 + l15 * 16);
            bf16x8 v1h = *(const bf16x8*)(vb + (16 + l15) * 16);
            bf16x8 v1l = *(const bf16x8*)(vb + 4224 + (16 + l15) * 16);
            o0 = MFMA16(pf, v0h, o0, 0, 0, 0);
            o0 = MFMA16(pf, v0l, o0, 0, 0, 0);
            o1 = MFMA16(pf, v1h, o1, 0, 0, 0);
            o1 = MFMA16(pf, v1l, o1, 0, 0, 0);
        }
        bufv ^= 1;

        #pragma unroll
        for (int reg = 0; reg < 4; ++reg) {
            int s = rowbase + lg * 4 + reg;
            {
                int d = 32 * ccc + l15;
                ob[(s * 32 + h * 8 + (d >> 7)) * 128 + (d & 127)] = o0[reg];
            }
            {
                int d = 32 * ccc + 16 + l15;
                ob[(s * 32 + h * 8 + (d >> 7)) * 128 + (d & 127)] = o1[reg];
            }
        }
    }
}

constexpr int LDS_B = 128 * 132 + 64 * 132;

__global__ __launch_bounds__(256, 1)
void proj_inplace(const float* __restrict__ pw,
                  const float* __restrict__ pb,
                  float* __restrict__ io)
{
    __shared__ float lds[LDS_B];
    float* pwt  = lds;
    float* rows = lds + 128 * 132;
    const int tid = threadIdx.x;

    for (int idx = tid; idx < 128 * 128; idx += 256) {
        const int c = idx >> 7, cp = idx & 127;
        pwt[cp * 132 + c] = pw[idx];
    }
    const int rb = tid >> 5;
    const int cg = tid & 31;
    const float4 pbv = *(const float4*)(pb + cg * 4);

    for (int it = 0; it < 8; ++it) {
        const size_t base = ((size_t)blockIdx.x * 8 + it) * 64;
        __syncthreads();
        for (int f = tid; f < 64 * 32; f += 256) {
            const int r = f >> 5, c4 = f & 31;
            *(float4*)(rows + r * 132 + c4 * 4) =
                *(const float4*)(io + (base + r) * 128 + c4 * 4);
        }
        __syncthreads();
        float acc[8][4] = {};
        #pragma unroll 2
        for (int cp = 0; cp < 128; ++cp) {
            const float4 wv = *(const float4*)(pwt + cp * 132 + cg * 4);
            #pragma unroll
            for (int rr = 0; rr < 8; ++rr) {
                const float xv = rows[(rb * 8 + rr) * 132 + cp];
                acc[rr][0] += xv * wv.x;
                acc[rr][1] += xv * wv.y;
                acc[rr][2] += xv * wv.z;
                acc[rr][3] += xv * wv.w;
            }
        }
        #pragma unroll
        for (int rr = 0; rr < 8; ++rr) {
            float4 o;
            o.x = acc[rr][0] + pbv.x;
            o.y = acc[rr][1] + pbv.y;
            o.z = acc[rr][2] + pbv.z;
            o.w = acc[rr][3] + pbv.w;
            *(float4*)(io + (base + rb * 8 + rr) * 128 + cg * 4) = o;
        }
    }
}

extern "C" void kernel_launch(void* const* d_in, const int* in_sizes, int n_in,
                              void* d_out, int out_size, void* d_ws, size_t ws_size,
                              hipStream_t stream)
{
    const float* x          = (const float*)d_in[0];
    const float* qkv_w      = (const float*)d_in[1];
    const float* qkv_b      = (const float*)d_in[2];
    const float* proj_w     = (const float*)d_in[3];
    const float* proj_b     = (const float*)d_in[4];
    const float* bias_table = (const float*)d_in[5];
    float* out = (float*)d_out;

    if (ws_size >= 262144 && d_ws != nullptr) {
        unsigned short* wsp = (unsigned short*)d_ws;
        split_w<<<dim3(192), dim3(256), 0, stream>>>(qkv_w, wsp);
        split_pw<<<dim3(64), dim3(256), 0, stream>>>(proj_w, wsp + 98304);
        attn_mfma3<<<dim3(512), dim3(512), 0, stream>>>(x, qkv_b, bias_table, wsp, out);
        proj_mfma<<<dim3(4096), dim3(256), 0, stream>>>(wsp + 98304, proj_b, out);
    } else if (ws_size >= 196608 && d_ws != nullptr) {
        unsigned short* wsp = (unsigned short*)d_ws;
        split_w<<<dim3(192), dim3(256), 0, stream>>>(qkv_w, wsp);
        attn_mfma<<<dim3(512), dim3(256), 0, stream>>>(x, qkv_b, bias_table, wsp, out);
        proj_inplace<<<dim3(512), dim3(256), 0, stream>>>(proj_w, proj_b, out);
    }
}

// Round 7
// 202.038 us; speedup vs baseline: 6.2297x; 1.4555x over previous
//
#include <hip/hip_runtime.h>
#include <cmath>

// Problem: x(128,64,32,128) f32; qkv_w(384,128); qkv_b(384); proj_w(128,128);
// proj_b(128); bias_table(225,4). H=4, D=1024 (merged N*C/H), scale=32^-0.5.
// qkv elem (b,s,t,h,d): rem=t*4096+h*1024+d; n=rem/384; j=rem%384 (128-chunks never straddle n; j0 in {0,128,256}).
// attn out (b,s,h,d) -> proj row = s*32+h*8+(d>>7), col = d&127.
// Per-batch strides: x = 262144 floats; out = 262144 floats.

typedef short bf16x8 __attribute__((ext_vector_type(8)));
typedef float f32x4  __attribute__((ext_vector_type(4)));
#define MFMA16 __builtin_amdgcn_mfma_f32_16x16x32_bf16

__device__ __forceinline__ unsigned rne16(float f) {
    unsigned u = __float_as_uint(f);
    return (u + 0x7fffu + ((u >> 16) & 1u)) & 0xffff0000u;   // bf16 RNE, kept in high bits
}
__device__ __forceinline__ void cvt8(float4 a, float4 b, bf16x8& H, bf16x8& L) {
    float f[8] = {a.x, a.y, a.z, a.w, b.x, b.y, b.z, b.w};
    #pragma unroll
    for (int i = 0; i < 8; ++i) {
        unsigned r = rne16(f[i]);
        H[i] = (short)(r >> 16);
        float fh = __uint_as_float(r);
        L[i] = (short)(rne16(f[i] - fh) >> 16);
    }
}
__device__ __forceinline__ void cvt8h(float4 a, float4 b, bf16x8& H) {
    float f[8] = {a.x, a.y, a.z, a.w, b.x, b.y, b.z, b.w};
    #pragma unroll
    for (int i = 0; i < 8; ++i) H[i] = (short)(rne16(f[i]) >> 16);
}

// ---------------- pre-kernels: split weights into hi/lo bf16, B-frag layouts ----------------
__global__ void split_w(const float* __restrict__ qw, unsigned short* __restrict__ wsp) {
    int idx = blockIdx.x * 256 + threadIdx.x;          // 0..49151
    if (idx >= 49152) return;
    int j = idx >> 7, c = idx & 127;
    float v = qw[idx];
    unsigned r = rne16(v);
    unsigned rl = rne16(v - __uint_as_float(r));
    int dest = (((j >> 5) * 16 + (c >> 3)) * 32 + (j & 31)) * 8 + (c & 7);
    wsp[dest] = (unsigned short)(r >> 16);
    wsp[49152 + dest] = (unsigned short)(rl >> 16);
}
__global__ void split_pw(const float* __restrict__ pw, unsigned short* __restrict__ pwsp) {
    int idx = blockIdx.x * 256 + threadIdx.x;          // 0..16383
    if (idx >= 16384) return;
    int cp = idx >> 7, c = idx & 127;
    float v = pw[idx];
    unsigned r = rne16(v);
    unsigned rl = rne16(v - __uint_as_float(r));
    int dest = ((c >> 3) * 128 + cp) * 8 + (c & 7);
    pwsp[dest] = (unsigned short)(r >> 16);
    pwsp[16384 + dest] = (unsigned short)(rl >> 16);
}

// ---------------- Kernel A4: fused qkv + attention, single-bf16 qkv, dbuf, 1 barrier/iter ----------------
// wave w: qt=w&3 (16-row tile), ch=w>>2 (64-col half)
// LDS: QC0 0, KC0 16640, QC1 33280, KC1 49920   ([d>>3 16x1040][s 64][d&7] bf16)
//      P 66560..74880 ([t>>3 8x1040][s][t&7] bf16) ; SMA 74880 [2][64] f32 ; SMB 75392
//      VC0 overlays QC0 (0..16640), VC1 overlays KC0 (16640..33280)  ([t>>3 8x2080][d 128][t&7])
constexpr int A4_QC0 = 0,     A4_KC0 = 16640;
constexpr int A4_QC1 = 33280, A4_KC1 = 49920;
constexpr int A4_P   = 66560;
constexpr int A4_SMA = 74880;
constexpr int A4_SMB = 75392;
constexpr int A4_VC0 = 0,     A4_VC1 = 16640;
constexpr int A4_LDS = 75904;

__global__ __launch_bounds__(512, 4)
void attn_mfma4(const float* __restrict__ x,
                const float* __restrict__ qkv_b,
                const float* __restrict__ bias_table,
                const unsigned short* __restrict__ wsp,
                float* __restrict__ out)
{
    __shared__ __attribute__((aligned(128))) char lds[A4_LDS];
    const int tid = threadIdx.x;
    const int lane = tid & 63;
    const int w = tid >> 6;
    const int l15 = lane & 15, lg = lane >> 4;
    const int qt = w & 3, ch = w >> 2;
    const int rowbase = qt * 16;
    const int b = blockIdx.x >> 2, h = blockIdx.x & 3;
    const float* __restrict__ xb = x + (size_t)b * 262144;
    const float* xrow0 = xb + (size_t)(rowbase + l15) * 4096 + lg * 8;

    bf16x8 aH[4];           // q-side / v-side x-frag cache (single bf16)
    bf16x8 kH[4];           // k-side x-frag cache
    int cur_na = -1, cur_nk = -1;

    auto loadfrags = [&](int n0, bf16x8 (&H)[4]) {
        const float* p = xrow0 + (size_t)n0 * 128;
        #pragma unroll
        for (int ks = 0; ks < 4; ++ks) {
            float4 a = *(const float4*)(p + ks * 32);
            float4 c = *(const float4*)(p + ks * 32 + 4);
            cvt8h(a, c, H[ks]);
        }
    };

    // production: rows = own 16, cols = wave's 64-half of [j0..j0+127], K=128, single pass
    auto prod64 = [&](const bf16x8 (&H)[4], int j0, f32x4 (&acc)[4]) {
        const unsigned short* wb = wsp + (size_t)(j0 >> 5) * 4096;
        #pragma unroll
        for (int ks = 0; ks < 4; ++ks) {
            #pragma unroll
            for (int ct = 0; ct < 4; ++ct) {
                int gct = ch * 4 + ct;
                int ro = (gct >> 1) * 4096 + ((ks * 4 + lg) * 32 + (gct & 1) * 16 + l15) * 8;
                bf16x8 bh = *(const bf16x8*)(wb + ro);
                acc[ct] = MFMA16(H[ks], bh, acc[ct], 0, 0, 0);
            }
        }
    };

    // store production tile (+bias) as single bf16 into [d>>3][s][d&7]
    auto storeP64 = [&](int base, f32x4 (&acc)[4], int j0) {
        #pragma unroll
        for (int ct = 0; ct < 4; ++ct) {
            int d = (ch * 4 + ct) * 16 + l15;
            float bias = qkv_b[j0 + d];
            int dofs = (d >> 3) * 1040 + (d & 7) * 2;
            #pragma unroll
            for (int reg = 0; reg < 4; ++reg) {
                int s = rowbase + lg * 4 + reg;
                *(unsigned short*)(lds + base + dofs + s * 16) =
                    (unsigned short)(rne16(acc[ct][reg] + bias) >> 16);
            }
        }
    };

    // ---------------- QK^T phase (8 iters of 128 d, dbuf, 1 barrier/iter) ----------------
    f32x4 accQK[2];
    #pragma unroll
    for (int tt = 0; tt < 2; ++tt) accQK[tt] = (f32x4){0.f, 0.f, 0.f, 0.f};

    for (int cc = 0; cc < 8; ++cc) {
        int qcb = (cc & 1) ? A4_QC1 : A4_QC0;
        int kcb = (cc & 1) ? A4_KC1 : A4_KC0;
        int remq = h * 1024 + 128 * cc;
        int nq = remq / 384, j0q = remq - nq * 384;
        int remk = 4096 + h * 1024 + 128 * cc;
        int nk = remk / 384, j0k = remk - nk * 384;
        if (nq != cur_na) { loadfrags(nq, aH); cur_na = nq; }
        if (nk != cur_nk) { loadfrags(nk, kH); cur_nk = nk; }

        f32x4 qa[4];
        #pragma unroll
        for (int i = 0; i < 4; ++i) qa[i] = (f32x4){0.f, 0.f, 0.f, 0.f};
        prod64(aH, j0q, qa);
        storeP64(qcb, qa, j0q);

        f32x4 ka[4];
        #pragma unroll
        for (int i = 0; i < 4; ++i) ka[i] = (f32x4){0.f, 0.f, 0.f, 0.f};
        prod64(kH, j0k, ka);
        storeP64(kcb, ka, j0k);

        __syncthreads();   // buf(cc&1) ready; buf((cc-1)&1) reads all completed >=1 barrier ago

        #pragma unroll
        for (int kst = 0; kst < 4; ++kst) {
            int grp = (kst * 4 + lg) * 1040;
            bf16x8 qh = *(const bf16x8*)(lds + qcb + grp + (rowbase + l15) * 16);
            #pragma unroll
            for (int tt = 0; tt < 2; ++tt) {
                int trow = ((ch * 2 + tt) * 16 + l15) * 16;
                bf16x8 kh = *(const bf16x8*)(lds + kcb + grp + trow);
                accQK[tt] = MFMA16(qh, kh, accQK[tt], 0, 0, 0);
            }
        }
    }

    // ---------------- softmax: rows s = rowbase+lg*4+reg, wave holds t-half (32) ----------------
    {
        const float scale = 0.17677669529663687f;
        float* smA = (float*)(lds + A4_SMA);
        float* smB = (float*)(lds + A4_SMB);
        float ex[4][2];
        #pragma unroll
        for (int reg = 0; reg < 4; ++reg) {
            int s = rowbase + lg * 4 + reg;
            int i1 = s >> 3, j1 = s & 7;
            float m = -1e30f;
            #pragma unroll
            for (int tt = 0; tt < 2; ++tt) {
                int t = (ch * 2 + tt) * 16 + l15;
                int i2 = t >> 3, j2 = t & 7;
                float L = accQK[tt][reg] * scale
                        + bias_table[((i1 - i2 + 7) * 15 + (j1 - j2 + 7)) * 4 + h];
                ex[reg][tt] = L;
                m = fmaxf(m, L);
            }
            m = fmaxf(m, __shfl_xor(m, 1));
            m = fmaxf(m, __shfl_xor(m, 2));
            m = fmaxf(m, __shfl_xor(m, 4));
            m = fmaxf(m, __shfl_xor(m, 8));
            if (l15 == 0) smA[ch * 64 + s] = m;
        }
        __syncthreads();   // also guarantees ALL QK reads done (before VC overlays QC0/KC0)
        #pragma unroll
        for (int reg = 0; reg < 4; ++reg) {
            int s = rowbase + lg * 4 + reg;
            float mg = fmaxf(smA[s], smA[64 + s]);
            float e0 = __expf(ex[reg][0] - mg);
            float e1 = __expf(ex[reg][1] - mg);
            ex[reg][0] = e0; ex[reg][1] = e1;
            float sum = e0 + e1;
            sum += __shfl_xor(sum, 1);
            sum += __shfl_xor(sum, 2);
            sum += __shfl_xor(sum, 4);
            sum += __shfl_xor(sum, 8);
            if (l15 == 0) smB[ch * 64 + s] = sum;
        }
        __syncthreads();
        #pragma unroll
        for (int reg = 0; reg < 4; ++reg) {
            int s = rowbase + lg * 4 + reg;
            float inv = 1.f / (smB[s] + smB[64 + s]);
            #pragma unroll
            for (int tt = 0; tt < 2; ++tt) {
                int t = (ch * 2 + tt) * 16 + l15;
                int off = (t >> 3) * 1040 + s * 16 + (t & 7) * 2;
                *(unsigned short*)(lds + A4_P + off) =
                    (unsigned short)(rne16(ex[reg][tt] * inv) >> 16);
            }
        }
    }
    // P visibility to other waves: covered by the barrier inside PV iter 0.

    // ---------------- PV phase (8 iters of 128 d, dbuf, 1 barrier/iter) ----------------
    cur_na = -1;
    float* ob = out + (size_t)b * 262144;
    for (int cc = 0; cc < 8; ++cc) {
        int vcb = (cc & 1) ? A4_VC1 : A4_VC0;
        int remv = 8192 + h * 1024 + 128 * cc;
        int nv = remv / 384, j0v = remv - nv * 384;
        if (nv != cur_na) { loadfrags(nv, aH); cur_na = nv; }

        f32x4 va[4];
        #pragma unroll
        for (int i = 0; i < 4; ++i) va[i] = (f32x4){0.f, 0.f, 0.f, 0.f};
        prod64(aH, j0v, va);

        // transposed store into VC [t>>3][d][t&7], single bf16
        #pragma unroll
        for (int ct = 0; ct < 4; ++ct) {
            int d = (ch * 4 + ct) * 16 + l15;
            float bias = qkv_b[j0v + d];
            #pragma unroll
            for (int reg = 0; reg < 4; ++reg) {
                int t = rowbase + lg * 4 + reg;
                int off = (t >> 3) * 2080 + d * 16 + (t & 7) * 2;
                *(unsigned short*)(lds + vcb + off) =
                    (unsigned short)(rne16(va[ct][reg] + bias) >> 16);
            }
        }
        __syncthreads();   // VC(cc&1) ready; (and on cc=0, P ready)

        f32x4 o[4];
        #pragma unroll
        for (int i = 0; i < 4; ++i) o[i] = (f32x4){0.f, 0.f, 0.f, 0.f};
        #pragma unroll
        for (int kst = 0; kst < 2; ++kst) {
            bf16x8 pf = *(const bf16x8*)(lds + A4_P + (kst * 4 + lg) * 1040 + (rowbase + l15) * 16);
            int vgrp = (kst * 4 + lg) * 2080;
            #pragma unroll
            for (int dt = 0; dt < 4; ++dt) {
                int drow = ((ch * 4 + dt) * 16 + l15) * 16;
                bf16x8 vh = *(const bf16x8*)(lds + vcb + vgrp + drow);
                o[dt] = MFMA16(pf, vh, o[dt], 0, 0, 0);
            }
        }

        #pragma unroll
        for (int reg = 0; reg < 4; ++reg) {
            int s = rowbase + lg * 4 + reg;
            float* orow = ob + (size_t)(s * 32 + h * 8 + cc) * 128;
            #pragma unroll
            for (int dt = 0; dt < 4; ++dt)
                orow[(ch * 4 + dt) * 16 + l15] = o[dt][reg];
        }
    }
}

// ---------------- Kernel B2: proj via MFMA, register-only (at HBM roofline) ----------------
__global__ __launch_bounds__(256, 4)
void proj_mfma(const unsigned short* __restrict__ pwsp,
               const float* __restrict__ pb,
               float* __restrict__ io)
{
    const int tid = threadIdx.x;
    const int lane = tid & 63;
    const int w = tid >> 6;
    const int l15 = lane & 15, lg = lane >> 4;
    const size_t rbase = (size_t)blockIdx.x * 64 + w * 16;

    const float* rp = io + (rbase + l15) * 128 + lg * 8;
    bf16x8 aH[4], aL[4];
    #pragma unroll
    for (int ks = 0; ks < 4; ++ks) {
        float4 a = *(const float4*)(rp + ks * 32);
        float4 c = *(const float4*)(rp + ks * 32 + 4);
        cvt8(a, c, aH[ks], aL[ks]);
    }

    f32x4 acc[8];
    #pragma unroll
    for (int i = 0; i < 8; ++i) acc[i] = (f32x4){0.f, 0.f, 0.f, 0.f};

    #pragma unroll
    for (int ks = 0; ks < 4; ++ks) {
        #pragma unroll
        for (int ct = 0; ct < 8; ++ct) {
            int ro = ((ks * 4 + lg) * 128 + ct * 16 + l15) * 8;
            bf16x8 bh = *(const bf16x8*)(pwsp + ro);
            bf16x8 bl = *(const bf16x8*)(pwsp + 16384 + ro);
            acc[ct] = MFMA16(aH[ks], bh, acc[ct], 0, 0, 0);
            acc[ct] = MFMA16(aH[ks], bl, acc[ct], 0, 0, 0);
            acc[ct] = MFMA16(aL[ks], bh, acc[ct], 0, 0, 0);
        }
    }

    #pragma unroll
    for (int ct = 0; ct < 8; ++ct) {
        float bias = pb[ct * 16 + l15];
        #pragma unroll
        for (int reg = 0; reg < 4; ++reg)
            io[(rbase + lg * 4 + reg) * 128 + ct * 16 + l15] = acc[ct][reg] + bias;
    }
}

// ---------------- round-4 kernels (fallback path, known-correct) ----------------
constexpr int QC_OFF = 0;
constexpr int KC_OFF = 8320;
constexpr int VC_OFF = 24960;
constexpr int P_OFF  = 41856;
constexpr int LDS_TOT = 50176;

__global__ __launch_bounds__(256, 2)
void attn_mfma(const float* __restrict__ x,
               const float* __restrict__ qkv_b,
               const float* __restrict__ bias_table,
               const unsigned short* __restrict__ wsp,
               float* __restrict__ out)
{
    __shared__ __attribute__((aligned(128))) char lds[LDS_TOT];
    const int tid = threadIdx.x;
    const int lane = tid & 63;
    const int w = tid >> 6;
    const int l15 = lane & 15, lg = lane >> 4;
    const int rowbase = 16 * w;
    const int b = blockIdx.x >> 2, h = blockIdx.x & 3;
    const float* __restrict__ xb = x + (size_t)b * 262144;
    const float* xrow0 = xb + ((size_t)(rowbase + l15) * 32) * 128 + lg * 8;

    bf16x8 aH[4], aL[4];
    bf16x8 kH[4], kL[4];
    int cur_na = -1, cur_nk = -1;

    auto loadfrags = [&](int n0, bf16x8 (&H)[4], bf16x8 (&L)[4]) {
        const float* p = xrow0 + (size_t)n0 * 128;
        #pragma unroll
        for (int ks = 0; ks < 4; ++ks) {
            float4 a = *(const float4*)(p + ks * 32);
            float4 c = *(const float4*)(p + ks * 32 + 4);
            cvt8(a, c, H[ks], L[ks]);
        }
    };

    auto mm_band = [&](const bf16x8 (&H)[4], const bf16x8 (&L)[4], int band,
                       f32x4& a0, f32x4& a1) {
        const unsigned short* wb = wsp + (size_t)band * 4096;
        #pragma unroll
        for (int ks = 0; ks < 4; ++ks) {
            int ro = ((ks * 4 + lg) * 32 + l15) * 8;
            bf16x8 b0h = *(const bf16x8*)(wb + ro);
            bf16x8 b0l = *(const bf16x8*)(wb + 49152 + ro);
            bf16x8 b1h = *(const bf16x8*)(wb + ro + 128);
            bf16x8 b1l = *(const bf16x8*)(wb + 49152 + ro + 128);
            a0 = MFMA16(H[ks], b0h, a0, 0, 0, 0);
            a0 = MFMA16(H[ks], b0l, a0, 0, 0, 0);
            a0 = MFMA16(L[ks], b0h, a0, 0, 0, 0);
            a1 = MFMA16(H[ks], b1h, a1, 0, 0, 0);
            a1 = MFMA16(H[ks], b1l, a1, 0, 0, 0);
            a1 = MFMA16(L[ks], b1h, a1, 0, 0, 0);
        }
    };

    auto store_rc = [&](char* base, f32x4 a0, f32x4 a1, float b0, float b1) {
        #pragma unroll
        for (int reg = 0; reg < 4; ++reg) {
            int s = rowbase + lg * 4 + reg;
            {
                float v = a0[reg] + b0;
                int i = l15;
                int off = (i >> 3) * 1040 + s * 16 + (i & 7) * 2;
                unsigned r = rne16(v);
                *(unsigned short*)(base + off) = (unsigned short)(r >> 16);
                *(unsigned short*)(base + 4160 + off) =
                    (unsigned short)(rne16(v - __uint_as_float(r)) >> 16);
            }
            {
                float v = a1[reg] + b1;
                int i = 16 + l15;
                int off = (i >> 3) * 1040 + s * 16 + (i & 7) * 2;
                unsigned r = rne16(v);
                *(unsigned short*)(base + off) = (unsigned short)(r >> 16);
                *(unsigned short*)(base + 4160 + off) =
                    (unsigned short)(rne16(v - __uint_as_float(r)) >> 16);
            }
        }
    };

    f32x4 accQK[4];
    #pragma unroll
    for (int tt = 0; tt < 4; ++tt) accQK[tt] = (f32x4){0.f, 0.f, 0.f, 0.f};

    int buf = 0;
    for (int ccc = 0; ccc < 32; ++ccc) {
        int remq = h * 1024 + 32 * ccc;
        int nq = remq / 384, j0q = remq - nq * 384, bandq = j0q >> 5;
        int remk = 4096 + h * 1024 + 32 * ccc;
        int nk = remk / 384, j0k = remk - nk * 384, bandk = j0k >> 5;
        if (nq != cur_na) { loadfrags(nq, aH, aL); cur_na = nq; }
        if (nk != cur_nk) { loadfrags(nk, kH, kL); cur_nk = nk; }

        f32x4 q0 = (f32x4){0.f,0.f,0.f,0.f}, q1 = (f32x4){0.f,0.f,0.f,0.f};
        mm_band(aH, aL, bandq, q0, q1);
        store_rc(lds + QC_OFF, q0, q1, qkv_b[j0q + l15], qkv_b[j0q + 16 + l15]);

        f32x4 k0 = (f32x4){0.f,0.f,0.f,0.f}, k1 = (f32x4){0.f,0.f,0.f,0.f};
        mm_band(kH, kL, bandk, k0, k1);
        store_rc(lds + KC_OFF + buf * 8320, k0, k1, qkv_b[j0k + l15], qkv_b[j0k + 16 + l15]);

        __syncthreads();

        const char* qc = lds + QC_OFF + lg * 1040 + (rowbase + l15) * 16;
        bf16x8 qah = *(const bf16x8*)qc;
        bf16x8 qal = *(const bf16x8*)(qc + 4160);
        #pragma unroll
        for (int tt = 0; tt < 4; ++tt) {
            const char* kc = lds + KC_OFF + buf * 8320 + lg * 1040 + (tt * 16 + l15) * 16;
            bf16x8 kbh = *(const bf16x8*)kc;
            bf16x8 kbl = *(const bf16x8*)(kc + 4160);
            accQK[tt] = MFMA16(qah, kbh, accQK[tt], 0, 0, 0);
            accQK[tt] = MFMA16(qah, kbl, accQK[tt], 0, 0, 0);
            accQK[tt] = MFMA16(qal, kbh, accQK[tt], 0, 0, 0);
        }
        buf ^= 1;
    }

    {
        const float scale = 0.17677669529663687f;
        #pragma unroll
        for (int reg = 0; reg < 4; ++reg) {
            int s = rowbase + lg * 4 + reg;
            int i1 = s >> 3, j1 = s & 7;
            float Lv[4];
            float m = -1e30f;
            #pragma unroll
            for (int tt = 0; tt < 4; ++tt) {
                int t = tt * 16 + l15;
                int i2 = t >> 3, j2 = t & 7;
                float L = accQK[tt][reg] * scale
                        + bias_table[((i1 - i2 + 7) * 15 + (j1 - j2 + 7)) * 4 + h];
                Lv[tt] = L;
                m = fmaxf(m, L);
            }
            m = fmaxf(m, __shfl_xor(m, 1));
            m = fmaxf(m, __shfl_xor(m, 2));
            m = fmaxf(m, __shfl_xor(m, 4));
            m = fmaxf(m, __shfl_xor(m, 8));
            float sum = 0.f;
            #pragma unroll
            for (int tt = 0; tt < 4; ++tt) { Lv[tt] = __expf(Lv[tt] - m); sum += Lv[tt]; }
            sum += __shfl_xor(sum, 1);
            sum += __shfl_xor(sum, 2);
            sum += __shfl_xor(sum, 4);
            sum += __shfl_xor(sum, 8);
            float inv = 1.f / sum;
            #pragma unroll
            for (int tt = 0; tt < 4; ++tt) {
                int t = tt * 16 + l15;
                int off = (t >> 3) * 1040 + s * 16 + (t & 7) * 2;
                *(unsigned short*)(lds + P_OFF + off) = (unsigned short)(rne16(Lv[tt] * inv) >> 16);
            }
        }
    }

    cur_na = -1;
    int bufv = 0;
    float* ob = out + (size_t)b * 262144;
    for (int ccc = 0; ccc < 32; ++ccc) {
        int remv = 8192 + h * 1024 + 32 * ccc;
        int nv = remv / 384, j0v = remv - nv * 384, bandv = j0v >> 5;
        if (nv != cur_na) { loadfrags(nv, aH, aL); cur_na = nv; }

        f32x4 v0 = (f32x4){0.f,0.f,0.f,0.f}, v1 = (f32x4){0.f,0.f,0.f,0.f};
        mm_band(aH, aL, bandv, v0, v1);
        {
            char* base = lds + VC_OFF + bufv * 8448;
            float b0 = qkv_b[j0v + l15], b1 = qkv_b[j0v + 16 + l15];
            #pragma unroll
            for (int reg = 0; reg < 4; ++reg) {
                int t = rowbase + lg * 4 + reg;
                {
                    float v = v0[reg] + b0;
                    int i = l15;
                    int off = (t >> 3) * 528 + i * 16 + (t & 7) * 2;
                    unsigned r = rne16(v);
                    *(unsigned short*)(base + off) = (unsigned short)(r >> 16);
                    *(unsigned short*)(base + 4224 + off) =
                        (unsigned short)(rne16(v - __uint_as_float(r)) >> 16);
                }
                {
                    float v = v1[reg] + b1;
                    int i = 16 + l15;
                    int off = (t >> 3) * 528 + i * 16 + (t & 7) * 2;
                    unsigned r = rne16(v);
                    *(unsigned short*)(base + off) = (unsigned short)(r >> 16);
                    *(unsigned short*)(base + 4224 + off) =
                        (unsigned short)(rne16(v - __uint_as_float(r)) >> 16);
                }
            }
        }
        __syncthreads();

        f32x4 o0 = (f32x4){0.f,0.f,0.f,0.f}, o1 = (f32x4){0.f,0.f,0.f,0.f};
        #pragma unroll
        for (int ks = 0; ks < 2; ++ks) {
            bf16x8 pf = *(const bf16x8*)(lds + P_OFF + (ks * 4 + lg) * 1040 + (rowbase + l15) * 16);
            const char* vb = lds + VC_OFF + bufv * 8448 + (ks * 4 + lg) * 528;
            bf16x8 v0h = *(const bf16x8*)(vb + l15 * 16);
            bf16x8 v0l = *(const bf16x8*)(vb + 4224 + l15 * 16);
            bf16x8 v1h = *(const bf16x8*)(vb + (16 + l15) * 16);
            bf16x8 v1l = *(const bf16x8*)(vb + 4224 + (16 + l15) * 16);
            o0 = MFMA16(pf, v0h, o0, 0, 0, 0);
            o0 = MFMA16(pf, v0l, o0, 0, 0, 0);
            o1 = MFMA16(pf, v1h, o1, 0, 0, 0);
            o1 = MFMA16(pf, v1l, o1, 0, 0, 0);
        }
        bufv ^= 1;

        #pragma unroll
        for (int reg = 0; reg < 4; ++reg) {
            int s = rowbase + lg * 4 + reg;
            {
                int d = 32 * ccc + l15;
                ob[(s * 32 + h * 8 + (d >> 7)) * 128 + (d & 127)] = o0[reg];
            }
            {
                int d = 32 * ccc + 16 + l15;
                ob[(s * 32 + h * 8 + (d >> 7)) * 128 + (d & 127)] = o1[reg];
            }
        }
    }
}

constexpr int LDS_B = 128 * 132 + 64 * 132;

__global__ __launch_bounds__(256, 1)
void proj_inplace(const float* __restrict__ pw,
                  const float* __restrict__ pb,
                  float* __restrict__ io)
{
    __shared__ float lds[LDS_B];
    float* pwt  = lds;
    float* rows = lds + 128 * 132;
    const int tid = threadIdx.x;

    for (int idx = tid; idx < 128 * 128; idx += 256) {
        const int c = idx >> 7, cp = idx & 127;
        pwt[cp * 132 + c] = pw[idx];
    }
    const int rb = tid >> 5;
    const int cg = tid & 31;
    const float4 pbv = *(const float4*)(pb + cg * 4);

    for (int it = 0; it < 8; ++it) {
        const size_t base = ((size_t)blockIdx.x * 8 + it) * 64;
        __syncthreads();
        for (int f = tid; f < 64 * 32; f += 256) {
            const int r = f >> 5, c4 = f & 31;
            *(float4*)(rows + r * 132 + c4 * 4) =
                *(const float4*)(io + (base + r) * 128 + c4 * 4);
        }
        __syncthreads();
        float acc[8][4] = {};
        #pragma unroll 2
        for (int cp = 0; cp < 128; ++cp) {
            const float4 wv = *(const float4*)(pwt + cp * 132 + cg * 4);
            #pragma unroll
            for (int rr = 0; rr < 8; ++rr) {
                const float xv = rows[(rb * 8 + rr) * 132 + cp];
                acc[rr][0] += xv * wv.x;
                acc[rr][1] += xv * wv.y;
                acc[rr][2] += xv * wv.z;
                acc[rr][3] += xv * wv.w;
            }
        }
        #pragma unroll
        for (int rr = 0; rr < 8; ++rr) {
            float4 o;
            o.x = acc[rr][0] + pbv.x;
            o.y = acc[rr][1] + pbv.y;
            o.z = acc[rr][2] + pbv.z;
            o.w = acc[rr][3] + pbv.w;
            *(float4*)(io + (base + rb * 8 + rr) * 128 + cg * 4) = o;
        }
    }
}

extern "C" void kernel_launch(void* const* d_in, const int* in_sizes, int n_in,
                              void* d_out, int out_size, void* d_ws, size_t ws_size,
                              hipStream_t stream)
{
    const float* x          = (const float*)d_in[0];
    const float* qkv_w      = (const float*)d_in[1];
    const float* qkv_b      = (const float*)d_in[2];
    const float* proj_w     = (const float*)d_in[3];
    const float* proj_b     = (const float*)d_in[4];
    const float* bias_table = (const float*)d_in[5];
    float* out = (float*)d_out;

    if (ws_size >= 262144 && d_ws != nullptr) {
        unsigned short* wsp = (unsigned short*)d_ws;
        split_w<<<dim3(192), dim3(256), 0, stream>>>(qkv_w, wsp);
        split_pw<<<dim3(64), dim3(256), 0, stream>>>(proj_w, wsp + 98304);
        attn_mfma4<<<dim3(512), dim3(512), 0, stream>>>(x, qkv_b, bias_table, wsp, out);
        proj_mfma<<<dim3(4096), dim3(256), 0, stream>>>(wsp + 98304, proj_b, out);
    } else if (ws_size >= 196608 && d_ws != nullptr) {
        unsigned short* wsp = (unsigned short*)d_ws;
        split_w<<<dim3(192), dim3(256), 0, stream>>>(qkv_w, wsp);
        attn_mfma<<<dim3(512), dim3(256), 0, stream>>>(x, qkv_b, bias_table, wsp, out);
        proj_inplace<<<dim3(512), dim3(256), 0, stream>>>(proj_w, proj_b, out);
    }
}

// Round 8
// 192.491 us; speedup vs baseline: 6.5386x; 1.0496x over previous
//
#include <hip/hip_runtime.h>
#include <cmath>

// Problem: x(128,64,32,128) f32; qkv_w(384,128); qkv_b(384); proj_w(128,128);
// proj_b(128); bias_table(225,4). H=4, D=1024 (merged N*C/H), scale=32^-0.5.
// qkv elem (b,s,t,h,d): rem=t*4096+h*1024+d; n=rem/384; j=rem%384 (128-chunks never straddle n).
// attn out (b,s,h,d) -> proj row = s*32+h*8+(d>>7), col = d&127.
// Per-batch strides: x = 262144 floats; out = 262144 floats.

typedef short bf16x8 __attribute__((ext_vector_type(8)));
typedef float f32x4  __attribute__((ext_vector_type(4)));
#define MFMA16 __builtin_amdgcn_mfma_f32_16x16x32_bf16

__device__ __forceinline__ unsigned rne16(float f) {
    unsigned u = __float_as_uint(f);
    return (u + 0x7fffu + ((u >> 16) & 1u)) & 0xffff0000u;   // bf16 RNE, kept in high bits
}
__device__ __forceinline__ void cvt8(float4 a, float4 b, bf16x8& H, bf16x8& L) {
    float f[8] = {a.x, a.y, a.z, a.w, b.x, b.y, b.z, b.w};
    #pragma unroll
    for (int i = 0; i < 8; ++i) {
        unsigned r = rne16(f[i]);
        H[i] = (short)(r >> 16);
        float fh = __uint_as_float(r);
        L[i] = (short)(rne16(f[i] - fh) >> 16);
    }
}
__device__ __forceinline__ void cvt8h(float4 a, float4 b, bf16x8& H) {
    float f[8] = {a.x, a.y, a.z, a.w, b.x, b.y, b.z, b.w};
    #pragma unroll
    for (int i = 0; i < 8; ++i) H[i] = (short)(rne16(f[i]) >> 16);
}

// ---------------- pre-kernels: split weights into hi/lo bf16, B-frag layouts ----------------
__global__ void split_w(const float* __restrict__ qw, unsigned short* __restrict__ wsp) {
    int idx = blockIdx.x * 256 + threadIdx.x;          // 0..49151
    if (idx >= 49152) return;
    int j = idx >> 7, c = idx & 127;
    float v = qw[idx];
    unsigned r = rne16(v);
    unsigned rl = rne16(v - __uint_as_float(r));
    int dest = (((j >> 5) * 16 + (c >> 3)) * 32 + (j & 31)) * 8 + (c & 7);
    wsp[dest] = (unsigned short)(r >> 16);
    wsp[49152 + dest] = (unsigned short)(rl >> 16);
}
__global__ void split_pw(const float* __restrict__ pw, unsigned short* __restrict__ pwsp) {
    int idx = blockIdx.x * 256 + threadIdx.x;          // 0..16383
    if (idx >= 16384) return;
    int cp = idx >> 7, c = idx & 127;
    float v = pw[idx];
    unsigned r = rne16(v);
    unsigned rl = rne16(v - __uint_as_float(r));
    int dest = ((c >> 3) * 128 + cp) * 8 + (c & 7);
    pwsp[dest] = (unsigned short)(r >> 16);
    pwsp[16384 + dest] = (unsigned short)(rl >> 16);
}

// ---------------- Kernel A5: fused qkv + attention, produce-ahead pipeline ----------------
// wave w: qt=w&3 (16-row tile), ch=w>>2 (64-col half)
// LDS: QC0 0, KC0 16640, QC1 33280, KC1 49920   ([d>>3 16x1040][s 64][d&7] bf16)
//      P 66560..74880 ([t>>3 8x1040][s][t&7] bf16) ; SMA 74880 [2][64] f32 ; SMB 75392
//      VC0 overlays QC0, VC1 overlays KC0  ([t>>3 8x2080][d 128][t&7])
// Pipeline: body cc produces tile cc+1 into buf[(cc+1)&1] while consuming tile cc
// from buf[cc&1]; ONE barrier at end of body. RAW/WAR separated by that barrier.
constexpr int A5_QC0 = 0,     A5_KC0 = 16640;
constexpr int A5_QC1 = 33280, A5_KC1 = 49920;
constexpr int A5_P   = 66560;
constexpr int A5_SMA = 74880;
constexpr int A5_SMB = 75392;
constexpr int A5_VC0 = 0,     A5_VC1 = 16640;
constexpr int A5_LDS = 75904;

__global__ __launch_bounds__(512, 4)
void attn_mfma5(const float* __restrict__ x,
                const float* __restrict__ qkv_b,
                const float* __restrict__ bias_table,
                const unsigned short* __restrict__ wsp,
                float* __restrict__ out)
{
    __shared__ __attribute__((aligned(128))) char lds[A5_LDS];
    const int tid = threadIdx.x;
    const int lane = tid & 63;
    const int w = tid >> 6;
    const int l15 = lane & 15, lg = lane >> 4;
    const int qt = w & 3, ch = w >> 2;
    const int rowbase = qt * 16;
    const int b = blockIdx.x >> 2, h = blockIdx.x & 3;
    const float* __restrict__ xb = x + (size_t)b * 262144;
    const float* xrow0 = xb + (size_t)(rowbase + l15) * 4096 + lg * 8;

    bf16x8 aH[4];           // q-side / v-side x-frag cache
    bf16x8 kH[4];           // k-side x-frag cache
    int cur_na = -1, cur_nk = -1;

    auto loadfrags = [&](int n0, bf16x8 (&H)[4]) {
        const float* p = xrow0 + (size_t)n0 * 128;
        #pragma unroll
        for (int ks = 0; ks < 4; ++ks) {
            float4 a = *(const float4*)(p + ks * 32);
            float4 c = *(const float4*)(p + ks * 32 + 4);
            cvt8h(a, c, H[ks]);
        }
    };

    // production: rows = own 16, cols = wave's 64-half of [j0..j0+127], K=128
    auto prod64 = [&](const bf16x8 (&H)[4], int j0, f32x4 (&acc)[4]) {
        const unsigned short* wb = wsp + (size_t)(j0 >> 5) * 4096;
        #pragma unroll
        for (int ks = 0; ks < 4; ++ks) {
            #pragma unroll
            for (int ct = 0; ct < 4; ++ct) {
                int gct = ch * 4 + ct;
                int ro = (gct >> 1) * 4096 + ((ks * 4 + lg) * 32 + (gct & 1) * 16 + l15) * 8;
                bf16x8 bh = *(const bf16x8*)(wb + ro);
                acc[ct] = MFMA16(H[ks], bh, acc[ct], 0, 0, 0);
            }
        }
    };

    // store production tile (+bias) as bf16 into [d>>3][s][d&7]
    auto storeP64 = [&](int base, f32x4 (&acc)[4], int j0) {
        #pragma unroll
        for (int ct = 0; ct < 4; ++ct) {
            int d = (ch * 4 + ct) * 16 + l15;
            float bias = qkv_b[j0 + d];
            int dofs = (d >> 3) * 1040 + (d & 7) * 2;
            #pragma unroll
            for (int reg = 0; reg < 4; ++reg) {
                int s = rowbase + lg * 4 + reg;
                *(unsigned short*)(lds + base + dofs + s * 16) =
                    (unsigned short)(rne16(acc[ct][reg] + bias) >> 16);
            }
        }
    };

    auto prodQK = [&](int cc) {
        int remq = h * 1024 + 128 * cc;
        int nq = remq / 384, j0q = remq - nq * 384;
        int remk = 4096 + h * 1024 + 128 * cc;
        int nk = remk / 384, j0k = remk - nk * 384;
        if (nq != cur_na) { loadfrags(nq, aH); cur_na = nq; }
        if (nk != cur_nk) { loadfrags(nk, kH); cur_nk = nk; }
        f32x4 qa[4];
        #pragma unroll
        for (int i = 0; i < 4; ++i) qa[i] = (f32x4){0.f, 0.f, 0.f, 0.f};
        prod64(aH, j0q, qa);
        storeP64((cc & 1) ? A5_QC1 : A5_QC0, qa, j0q);
        f32x4 ka[4];
        #pragma unroll
        for (int i = 0; i < 4; ++i) ka[i] = (f32x4){0.f, 0.f, 0.f, 0.f};
        prod64(kH, j0k, ka);
        storeP64((cc & 1) ? A5_KC1 : A5_KC0, ka, j0k);
    };

    // ---------------- QK^T phase: produce-ahead pipeline ----------------
    f32x4 accQK[2];
    #pragma unroll
    for (int tt = 0; tt < 2; ++tt) accQK[tt] = (f32x4){0.f, 0.f, 0.f, 0.f};

    prodQK(0);
    __syncthreads();          // tile 0 ready

    for (int cc = 0; cc < 8; ++cc) {
        if (cc < 7) prodQK(cc + 1);   // produce next (independent of consume below)

        int qcb = (cc & 1) ? A5_QC1 : A5_QC0;
        int kcb = (cc & 1) ? A5_KC1 : A5_KC0;
        #pragma unroll
        for (int kst = 0; kst < 4; ++kst) {
            int grp = (kst * 4 + lg) * 1040;
            bf16x8 qh = *(const bf16x8*)(lds + qcb + grp + (rowbase + l15) * 16);
            #pragma unroll
            for (int tt = 0; tt < 2; ++tt) {
                int trow = ((ch * 2 + tt) * 16 + l15) * 16;
                bf16x8 kh = *(const bf16x8*)(lds + kcb + grp + trow);
                accQK[tt] = MFMA16(qh, kh, accQK[tt], 0, 0, 0);
            }
        }
        __syncthreads();      // store(cc+1) complete; reads(cc) complete
    }

    // ---------------- softmax: rows s = rowbase+lg*4+reg, wave holds t-half (32) ----------------
    {
        const float scale = 0.17677669529663687f;
        float* smA = (float*)(lds + A5_SMA);
        float* smB = (float*)(lds + A5_SMB);
        float ex[4][2];
        #pragma unroll
        for (int reg = 0; reg < 4; ++reg) {
            int s = rowbase + lg * 4 + reg;
            int i1 = s >> 3, j1 = s & 7;
            float m = -1e30f;
            #pragma unroll
            for (int tt = 0; tt < 2; ++tt) {
                int t = (ch * 2 + tt) * 16 + l15;
                int i2 = t >> 3, j2 = t & 7;
                float L = accQK[tt][reg] * scale
                        + bias_table[((i1 - i2 + 7) * 15 + (j1 - j2 + 7)) * 4 + h];
                ex[reg][tt] = L;
                m = fmaxf(m, L);
            }
            m = fmaxf(m, __shfl_xor(m, 1));
            m = fmaxf(m, __shfl_xor(m, 2));
            m = fmaxf(m, __shfl_xor(m, 4));
            m = fmaxf(m, __shfl_xor(m, 8));
            if (l15 == 0) smA[ch * 64 + s] = m;
        }
        __syncthreads();
        #pragma unroll
        for (int reg = 0; reg < 4; ++reg) {
            int s = rowbase + lg * 4 + reg;
            float mg = fmaxf(smA[s], smA[64 + s]);
            float e0 = __expf(ex[reg][0] - mg);
            float e1 = __expf(ex[reg][1] - mg);
            ex[reg][0] = e0; ex[reg][1] = e1;
            float sum = e0 + e1;
            sum += __shfl_xor(sum, 1);
            sum += __shfl_xor(sum, 2);
            sum += __shfl_xor(sum, 4);
            sum += __shfl_xor(sum, 8);
            if (l15 == 0) smB[ch * 64 + s] = sum;
        }
        __syncthreads();
        #pragma unroll
        for (int reg = 0; reg < 4; ++reg) {
            int s = rowbase + lg * 4 + reg;
            float inv = 1.f / (smB[s] + smB[64 + s]);
            #pragma unroll
            for (int tt = 0; tt < 2; ++tt) {
                int t = (ch * 2 + tt) * 16 + l15;
                int off = (t >> 3) * 1040 + s * 16 + (t & 7) * 2;
                *(unsigned short*)(lds + A5_P + off) =
                    (unsigned short)(rne16(ex[reg][tt] * inv) >> 16);
            }
        }
    }

    // ---------------- PV phase: produce-ahead pipeline ----------------
    cur_na = -1;
    float* ob = out + (size_t)b * 262144;

    auto prodV = [&](int cc) {
        int remv = 8192 + h * 1024 + 128 * cc;
        int nv = remv / 384, j0v = remv - nv * 384;
        if (nv != cur_na) { loadfrags(nv, aH); cur_na = nv; }
        f32x4 va[4];
        #pragma unroll
        for (int i = 0; i < 4; ++i) va[i] = (f32x4){0.f, 0.f, 0.f, 0.f};
        prod64(aH, j0v, va);
        int vcb = (cc & 1) ? A5_VC1 : A5_VC0;
        #pragma unroll
        for (int ct = 0; ct < 4; ++ct) {
            int d = (ch * 4 + ct) * 16 + l15;
            float bias = qkv_b[j0v + d];
            #pragma unroll
            for (int reg = 0; reg < 4; ++reg) {
                int t = rowbase + lg * 4 + reg;
                int off = (t >> 3) * 2080 + d * 16 + (t & 7) * 2;
                *(unsigned short*)(lds + vcb + off) =
                    (unsigned short)(rne16(va[ct][reg] + bias) >> 16);
            }
        }
    };

    prodV(0);                 // writes VC0 (overlays QC0: last read >=3 barriers ago)
    __syncthreads();          // VC0 + P visible

    for (int cc = 0; cc < 8; ++cc) {
        if (cc < 7) prodV(cc + 1);

        int vcb = (cc & 1) ? A5_VC1 : A5_VC0;
        f32x4 o[4];
        #pragma unroll
        for (int i = 0; i < 4; ++i) o[i] = (f32x4){0.f, 0.f, 0.f, 0.f};
        #pragma unroll
        for (int kst = 0; kst < 2; ++kst) {
            bf16x8 pf = *(const bf16x8*)(lds + A5_P + (kst * 4 + lg) * 1040 + (rowbase + l15) * 16);
            int vgrp = (kst * 4 + lg) * 2080;
            #pragma unroll
            for (int dt = 0; dt < 4; ++dt) {
                int drow = ((ch * 4 + dt) * 16 + l15) * 16;
                bf16x8 vh = *(const bf16x8*)(lds + vcb + vgrp + drow);
                o[dt] = MFMA16(pf, vh, o[dt], 0, 0, 0);
            }
        }

        #pragma unroll
        for (int reg = 0; reg < 4; ++reg) {
            int s = rowbase + lg * 4 + reg;
            float* orow = ob + (size_t)(s * 32 + h * 8 + cc) * 128;
            #pragma unroll
            for (int dt = 0; dt < 4; ++dt)
                orow[(ch * 4 + dt) * 16 + l15] = o[dt][reg];
        }
        __syncthreads();
    }
}

// ---------------- Kernel B2: proj via MFMA, register-only (at HBM roofline) ----------------
__global__ __launch_bounds__(256, 4)
void proj_mfma(const unsigned short* __restrict__ pwsp,
               const float* __restrict__ pb,
               float* __restrict__ io)
{
    const int tid = threadIdx.x;
    const int lane = tid & 63;
    const int w = tid >> 6;
    const int l15 = lane & 15, lg = lane >> 4;
    const size_t rbase = (size_t)blockIdx.x * 64 + w * 16;

    const float* rp = io + (rbase + l15) * 128 + lg * 8;
    bf16x8 aH[4], aL[4];
    #pragma unroll
    for (int ks = 0; ks < 4; ++ks) {
        float4 a = *(const float4*)(rp + ks * 32);
        float4 c = *(const float4*)(rp + ks * 32 + 4);
        cvt8(a, c, aH[ks], aL[ks]);
    }

    f32x4 acc[8];
    #pragma unroll
    for (int i = 0; i < 8; ++i) acc[i] = (f32x4){0.f, 0.f, 0.f, 0.f};

    #pragma unroll
    for (int ks = 0; ks < 4; ++ks) {
        #pragma unroll
        for (int ct = 0; ct < 8; ++ct) {
            int ro = ((ks * 4 + lg) * 128 + ct * 16 + l15) * 8;
            bf16x8 bh = *(const bf16x8*)(pwsp + ro);
            bf16x8 bl = *(const bf16x8*)(pwsp + 16384 + ro);
            acc[ct] = MFMA16(aH[ks], bh, acc[ct], 0, 0, 0);
            acc[ct] = MFMA16(aH[ks], bl, acc[ct], 0, 0, 0);
            acc[ct] = MFMA16(aL[ks], bh, acc[ct], 0, 0, 0);
        }
    }

    #pragma unroll
    for (int ct = 0; ct < 8; ++ct) {
        float bias = pb[ct * 16 + l15];
        #pragma unroll
        for (int reg = 0; reg < 4; ++reg)
            io[(rbase + lg * 4 + reg) * 128 + ct * 16 + l15] = acc[ct][reg] + bias;
    }
}

// ---------------- round-4 kernels (fallback path, known-correct) ----------------
constexpr int QC_OFF = 0;
constexpr int KC_OFF = 8320;
constexpr int VC_OFF = 24960;
constexpr int P_OFF  = 41856;
constexpr int LDS_TOT = 50176;

__global__ __launch_bounds__(256, 2)
void attn_mfma(const float* __restrict__ x,
               const float* __restrict__ qkv_b,
               const float* __restrict__ bias_table,
               const unsigned short* __restrict__ wsp,
               float* __restrict__ out)
{
    __shared__ __attribute__((aligned(128))) char lds[LDS_TOT];
    const int tid = threadIdx.x;
    const int lane = tid & 63;
    const int w = tid >> 6;
    const int l15 = lane & 15, lg = lane >> 4;
    const int rowbase = 16 * w;
    const int b = blockIdx.x >> 2, h = blockIdx.x & 3;
    const float* __restrict__ xb = x + (size_t)b * 262144;
    const float* xrow0 = xb + ((size_t)(rowbase + l15) * 32) * 128 + lg * 8;

    bf16x8 aH[4], aL[4];
    bf16x8 kH[4], kL[4];
    int cur_na = -1, cur_nk = -1;

    auto loadfrags = [&](int n0, bf16x8 (&H)[4], bf16x8 (&L)[4]) {
        const float* p = xrow0 + (size_t)n0 * 128;
        #pragma unroll
        for (int ks = 0; ks < 4; ++ks) {
            float4 a = *(const float4*)(p + ks * 32);
            float4 c = *(const float4*)(p + ks * 32 + 4);
            cvt8(a, c, H[ks], L[ks]);
        }
    };

    auto mm_band = [&](const bf16x8 (&H)[4], const bf16x8 (&L)[4], int band,
                       f32x4& a0, f32x4& a1) {
        const unsigned short* wb = wsp + (size_t)band * 4096;
        #pragma unroll
        for (int ks = 0; ks < 4; ++ks) {
            int ro = ((ks * 4 + lg) * 32 + l15) * 8;
            bf16x8 b0h = *(const bf16x8*)(wb + ro);
            bf16x8 b0l = *(const bf16x8*)(wb + 49152 + ro);
            bf16x8 b1h = *(const bf16x8*)(wb + ro + 128);
            bf16x8 b1l = *(const bf16x8*)(wb + 49152 + ro + 128);
            a0 = MFMA16(H[ks], b0h, a0, 0, 0, 0);
            a0 = MFMA16(H[ks], b0l, a0, 0, 0, 0);
            a0 = MFMA16(L[ks], b0h, a0, 0, 0, 0);
            a1 = MFMA16(H[ks], b1h, a1, 0, 0, 0);
            a1 = MFMA16(H[ks], b1l, a1, 0, 0, 0);
            a1 = MFMA16(L[ks], b1h, a1, 0, 0, 0);
        }
    };

    auto store_rc = [&](char* base, f32x4 a0, f32x4 a1, float b0, float b1) {
        #pragma unroll
        for (int reg = 0; reg < 4; ++reg) {
            int s = rowbase + lg * 4 + reg;
            {
                float v = a0[reg] + b0;
                int i = l15;
                int off = (i >> 3) * 1040 + s * 16 + (i & 7) * 2;
                unsigned r = rne16(v);
                *(unsigned short*)(base + off) = (unsigned short)(r >> 16);
                *(unsigned short*)(base + 4160 + off) =
                    (unsigned short)(rne16(v - __uint_as_float(r)) >> 16);
            }
            {
                float v = a1[reg] + b1;
                int i = 16 + l15;
                int off = (i >> 3) * 1040 + s * 16 + (i & 7) * 2;
                unsigned r = rne16(v);
                *(unsigned short*)(base + off) = (unsigned short)(r >> 16);
                *(unsigned short*)(base + 4160 + off) =
                    (unsigned short)(rne16(v - __uint_as_float(r)) >> 16);
            }
        }
    };

    f32x4 accQK[4];
    #pragma unroll
    for (int tt = 0; tt < 4; ++tt) accQK[tt] = (f32x4){0.f, 0.f, 0.f, 0.f};

    int buf = 0;
    for (int ccc = 0; ccc < 32; ++ccc) {
        int remq = h * 1024 + 32 * ccc;
        int nq = remq / 384, j0q = remq - nq * 384, bandq = j0q >> 5;
        int remk = 4096 + h * 1024 + 32 * ccc;
        int nk = remk / 384, j0k = remk - nk * 384, bandk = j0k >> 5;
        if (nq != cur_na) { loadfrags(nq, aH, aL); cur_na = nq; }
        if (nk != cur_nk) { loadfrags(nk, kH, kL); cur_nk = nk; }

        f32x4 q0 = (f32x4){0.f,0.f,0.f,0.f}, q1 = (f32x4){0.f,0.f,0.f,0.f};
        mm_band(aH, aL, bandq, q0, q1);
        store_rc(lds + QC_OFF, q0, q1, qkv_b[j0q + l15], qkv_b[j0q + 16 + l15]);

        f32x4 k0 = (f32x4){0.f,0.f,0.f,0.f}, k1 = (f32x4){0.f,0.f,0.f,0.f};
        mm_band(kH, kL, bandk, k0, k1);
        store_rc(lds + KC_OFF + buf * 8320, k0, k1, qkv_b[j0k + l15], qkv_b[j0k + 16 + l15]);

        __syncthreads();

        const char* qc = lds + QC_OFF + lg * 1040 + (rowbase + l15) * 16;
        bf16x8 qah = *(const bf16x8*)qc;
        bf16x8 qal = *(const bf16x8*)(qc + 4160);
        #pragma unroll
        for (int tt = 0; tt < 4; ++tt) {
            const char* kc = lds + KC_OFF + buf * 8320 + lg * 1040 + (tt * 16 + l15) * 16;
            bf16x8 kbh = *(const bf16x8*)kc;
            bf16x8 kbl = *(const bf16x8*)(kc + 4160);
            accQK[tt] = MFMA16(qah, kbh, accQK[tt], 0, 0, 0);
            accQK[tt] = MFMA16(qah, kbl, accQK[tt], 0, 0, 0);
            accQK[tt] = MFMA16(qal, kbh, accQK[tt], 0, 0, 0);
        }
        buf ^= 1;
    }

    {
        const float scale = 0.17677669529663687f;
        #pragma unroll
        for (int reg = 0; reg < 4; ++reg) {
            int s = rowbase + lg * 4 + reg;
            int i1 = s >> 3, j1 = s & 7;
            float Lv[4];
            float m = -1e30f;
            #pragma unroll
            for (int tt = 0; tt < 4; ++tt) {
                int t = tt * 16 + l15;
                int i2 = t >> 3, j2 = t & 7;
                float L = accQK[tt][reg] * scale
                        + bias_table[((i1 - i2 + 7) * 15 + (j1 - j2 + 7)) * 4 + h];
                Lv[tt] = L;
                m = fmaxf(m, L);
            }
            m = fmaxf(m, __shfl_xor(m, 1));
            m = fmaxf(m, __shfl_xor(m, 2));
            m = fmaxf(m, __shfl_xor(m, 4));
            m = fmaxf(m, __shfl_xor(m, 8));
            float sum = 0.f;
            #pragma unroll
            for (int tt = 0; tt < 4; ++tt) { Lv[tt] = __expf(Lv[tt] - m); sum += Lv[tt]; }
            sum += __shfl_xor(sum, 1);
            sum += __shfl_xor(sum, 2);
            sum += __shfl_xor(sum, 4);
            sum += __shfl_xor(sum, 8);
            float inv = 1.f / sum;
            #pragma unroll
            for (int tt = 0; tt < 4; ++tt) {
                int t = tt * 16 + l15;
                int off = (t >> 3) * 1040 + s * 16 + (t & 7) * 2;
                *(unsigned short*)(lds + P_OFF + off) = (unsigned short)(rne16(Lv[tt] * inv) >> 16);
            }
        }
    }

    cur_na = -1;
    int bufv = 0;
    float* ob = out + (size_t)b * 262144;
    for (int ccc = 0; ccc < 32; ++ccc) {
        int remv = 8192 + h * 1024 + 32 * ccc;
        int nv = remv / 384, j0v = remv - nv * 384, bandv = j0v >> 5;
        if (nv != cur_na) { loadfrags(nv, aH, aL); cur_na = nv; }

        f32x4 v0 = (f32x4){0.f,0.f,0.f,0.f}, v1 = (f32x4){0.f,0.f,0.f,0.f};
        mm_band(aH, aL, bandv, v0, v1);
        {
            char* base = lds + VC_OFF + bufv * 8448;
            float b0 = qkv_b[j0v + l15], b1 = qkv_b[j0v + 16 + l15];
            #pragma unroll
            for (int reg = 0; reg < 4; ++reg) {
                int t = rowbase + lg * 4 + reg;
                {
                    float v = v0[reg] + b0;
                    int i = l15;
                    int off = (t >> 3) * 528 + i * 16 + (t & 7) * 2;
                    unsigned r = rne16(v);
                    *(unsigned short*)(base + off) = (unsigned short)(r >> 16);
                    *(unsigned short*)(base + 4224 + off) =
                        (unsigned short)(rne16(v - __uint_as_float(r)) >> 16);
                }
                {
                    float v = v1[reg] + b1;
                    int i = 16 + l15;
                    int off = (t >> 3) * 528 + i * 16 + (t & 7) * 2;
                    unsigned r = rne16(v);
                    *(unsigned short*)(base + off) = (unsigned short)(r >> 16);
                    *(unsigned short*)(base + 4224 + off) =
                        (unsigned short)(rne16(v - __uint_as_float(r)) >> 16);
                }
            }
        }
        __syncthreads();

        f32x4 o0 = (f32x4){0.f,0.f,0.f,0.f}, o1 = (f32x4){0.f,0.f,0.f,0.f};
        #pragma unroll
        for (int ks = 0; ks < 2; ++ks) {
            bf16x8 pf = *(const bf16x8*)(lds + P_OFF + (ks * 4 + lg) * 1040 + (rowbase + l15) * 16);
            const char* vb = lds + VC_OFF + bufv * 8448 + (ks * 4 + lg) * 528;
            bf16x8 v0h = *(const bf16x8*)(vb + l15 * 16);
            bf16x8 v0l = *(const bf16x8*)(vb + 4224 + l15 * 16);
            bf16x8 v1h = *(const bf16x8*)(vb + (16 + l15) * 16);
            bf16x8 v1l = *(const bf16x8*)(vb + 4224 + (16 + l15) * 16);
            o0 = MFMA16(pf, v0h, o0, 0, 0, 0);
            o0 = MFMA16(pf, v0l, o0, 0, 0, 0);
            o1 = MFMA16(pf, v1h, o1, 0, 0, 0);
            o1 = MFMA16(pf, v1l, o1, 0, 0, 0);
        }
        bufv ^= 1;

        #pragma unroll
        for (int reg = 0; reg < 4; ++reg) {
            int s = rowbase + lg * 4 + reg;
            {
                int d = 32 * ccc + l15;
                ob[(s * 32 + h * 8 + (d >> 7)) * 128 + (d & 127)] = o0[reg];
            }
            {
                int d = 32 * ccc + 16 + l15;
                ob[(s * 32 + h * 8 + (d >> 7)) * 128 + (d & 127)] = o1[reg];
            }
        }
    }
}

constexpr int LDS_B = 128 * 132 + 64 * 132;

__global__ __launch_bounds__(256, 1)
void proj_inplace(const float* __restrict__ pw,
                  const float* __restrict__ pb,
                  float* __restrict__ io)
{
    __shared__ float lds[LDS_B];
    float* pwt  = lds;
    float* rows = lds + 128 * 132;
    const int tid = threadIdx.x;

    for (int idx = tid; idx < 128 * 128; idx += 256) {
        const int c = idx >> 7, cp = idx & 127;
        pwt[cp * 132 + c] = pw[idx];
    }
    const int rb = tid >> 5;
    const int cg = tid & 31;
    const float4 pbv = *(const float4*)(pb + cg * 4);

    for (int it = 0; it < 8; ++it) {
        const size_t base = ((size_t)blockIdx.x * 8 + it) * 64;
        __syncthreads();
        for (int f = tid; f < 64 * 32; f += 256) {
            const int r = f >> 5, c4 = f & 31;
            *(float4*)(rows + r * 132 + c4 * 4) =
                *(const float4*)(io + (base + r) * 128 + c4 * 4);
        }
        __syncthreads();
        float acc[8][4] = {};
        #pragma unroll 2
        for (int cp = 0; cp < 128; ++cp) {
            const float4 wv = *(const float4*)(pwt + cp * 132 + cg * 4);
            #pragma unroll
            for (int rr = 0; rr < 8; ++rr) {
                const float xv = rows[(rb * 8 + rr) * 132 + cp];
                acc[rr][0] += xv * wv.x;
                acc[rr][1] += xv * wv.y;
                acc[rr][2] += xv * wv.z;
                acc[rr][3] += xv * wv.w;
            }
        }
        #pragma unroll
        for (int rr = 0; rr < 8; ++rr) {
            float4 o;
            o.x = acc[rr][0] + pbv.x;
            o.y = acc[rr][1] + pbv.y;
            o.z = acc[rr][2] + pbv.z;
            o.w = acc[rr][3] + pbv.w;
            *(float4*)(io + (base + rb * 8 + rr) * 128 + cg * 4) = o;
        }
    }
}

extern "C" void kernel_launch(void* const* d_in, const int* in_sizes, int n_in,
                              void* d_out, int out_size, void* d_ws, size_t ws_size,
                              hipStream_t stream)
{
    const float* x          = (const float*)d_in[0];
    const float* qkv_w      = (const float*)d_in[1];
    const float* qkv_b      = (const float*)d_in[2];
    const float* proj_w     = (const float*)d_in[3];
    const float* proj_b     = (const float*)d_in[4];
    const float* bias_table = (const float*)d_in[5];
    float* out = (float*)d_out;

    if (ws_size >= 262144 && d_ws != nullptr) {
        unsigned short* wsp = (unsigned short*)d_ws;
        split_w<<<dim3(192), dim3(256), 0, stream>>>(qkv_w, wsp);
        split_pw<<<dim3(64), dim3(256), 0, stream>>>(proj_w, wsp + 98304);
        attn_mfma5<<<dim3(512), dim3(512), 0, stream>>>(x, qkv_b, bias_table, wsp, out);
        proj_mfma<<<dim3(4096), dim3(256), 0, stream>>>(wsp + 98304, proj_b, out);
    } else if (ws_size >= 196608 && d_ws != nullptr) {
        unsigned short* wsp = (unsigned short*)d_ws;
        split_w<<<dim3(192), dim3(256), 0, stream>>>(qkv_w, wsp);
        attn_mfma<<<dim3(512), dim3(256), 0, stream>>>(x, qkv_b, bias_table, wsp, out);
        proj_inplace<<<dim3(512), dim3(256), 0, stream>>>(proj_w, proj_b, out);
    }
}